// Round 13
// baseline (571.358 us; speedup 1.0000x reference)
//
#include <hip/hip_runtime.h>
#include <hip/hip_bf16.h>
#include <cstddef>
#include <cstdint>

#define T_TOK   2048
#define HID     2048
#define NHEADS  32
#define NKV     8
#define HDIM    64
#define FFN_DIM 8192
#define QKV_N   3072

typedef __hip_bfloat16 bf16;
typedef __attribute__((ext_vector_type(8))) short short8;
typedef __attribute__((ext_vector_type(4))) float f32x4;
typedef __attribute__((ext_vector_type(4))) unsigned short us4;

typedef __attribute__((address_space(1))) const void cg_void;
typedef __attribute__((address_space(3))) void lds_void;

// ========== cast + transpose: W[K][N] f32 -> Wt[N][K] bf16 (vectorized) ====
__global__ __launch_bounds__(256) void cast_transpose(const float* __restrict__ in,
                                                      bf16* __restrict__ out,
                                                      int K, int N)
{
    __shared__ bf16 t[64][68];
    const int n0 = blockIdx.x * 64, k0 = blockIdx.y * 64;
    const int g = threadIdx.x & 15, r = threadIdx.x >> 4;
    #pragma unroll
    for (int p = 0; p < 4; ++p) {
        int kr = r + p*16;
        float4 v = *(const float4*)(in + (size_t)(k0 + kr) * N + n0 + g*4);
        t[kr][g*4+0] = __float2bfloat16(v.x);
        t[kr][g*4+1] = __float2bfloat16(v.y);
        t[kr][g*4+2] = __float2bfloat16(v.z);
        t[kr][g*4+3] = __float2bfloat16(v.w);
    }
    __syncthreads();
    #pragma unroll
    for (int p = 0; p < 4; ++p) {
        int nr = r + p*16;
        us4 pk;
        #pragma unroll
        for (int i = 0; i < 4; ++i)
            pk[i] = __bfloat16_as_ushort(t[g*4+i][nr]);
        *(us4*)(out + (size_t)(n0 + nr) * K + k0 + g*4) = pk;
    }
}

// interleaved variant for gate/up fusion: col n -> row (n/32)*64 + is_up*32 + n%32
__global__ __launch_bounds__(256) void cast_ilv(const float* __restrict__ in,
                                                bf16* __restrict__ out,
                                                int N, int is_up)
{
    __shared__ bf16 t[64][68];
    const int n0 = blockIdx.x * 64, k0 = blockIdx.y * 64;
    const int g = threadIdx.x & 15, r = threadIdx.x >> 4;
    #pragma unroll
    for (int p = 0; p < 4; ++p) {
        int kr = r + p*16;
        float4 v = *(const float4*)(in + (size_t)(k0 + kr) * N + n0 + g*4);
        t[kr][g*4+0] = __float2bfloat16(v.x);
        t[kr][g*4+1] = __float2bfloat16(v.y);
        t[kr][g*4+2] = __float2bfloat16(v.z);
        t[kr][g*4+3] = __float2bfloat16(v.w);
    }
    __syncthreads();
    #pragma unroll
    for (int p = 0; p < 4; ++p) {
        int nr = r + p*16;
        int n = n0 + nr;
        int rr = ((n >> 5) << 6) + (is_up << 5) + (n & 31);
        us4 pk;
        #pragma unroll
        for (int i = 0; i < 4; ++i)
            pk[i] = __bfloat16_as_ushort(t[g*4+i][nr]);
        *(us4*)(out + (size_t)rr * HID + k0 + g*4) = pk;
    }
}

// ===================== RMSNorm (f32 in -> bf16 out) ========================
__global__ __launch_bounds__(256) void rmsnorm_kernel(const float* __restrict__ x,
                                                      const float* __restrict__ w,
                                                      bf16* __restrict__ out)
{
    __shared__ float sm[4];
    const int row = blockIdx.x, tid = threadIdx.x;
    const float4* xr = (const float4*)(x + (size_t)row * HID);
    float4 a = xr[tid], b = xr[tid + 256];
    float ss = a.x*a.x + a.y*a.y + a.z*a.z + a.w*a.w
             + b.x*b.x + b.y*b.y + b.z*b.z + b.w*b.w;
    #pragma unroll
    for (int off = 32; off; off >>= 1) ss += __shfl_down(ss, off);
    if ((tid & 63) == 0) sm[tid >> 6] = ss;
    __syncthreads();
    float sc = rsqrtf((sm[0] + sm[1] + sm[2] + sm[3]) * (1.0f / HID) + 1e-5f);
    const float4* wr = (const float4*)w;
    float4 w0 = wr[tid], w1 = wr[tid + 256];
    bf16* o = out + (size_t)row * HID;
    o[tid*4+0] = __float2bfloat16(a.x * sc * w0.x);
    o[tid*4+1] = __float2bfloat16(a.y * sc * w0.y);
    o[tid*4+2] = __float2bfloat16(a.z * sc * w0.z);
    o[tid*4+3] = __float2bfloat16(a.w * sc * w0.w);
    o[1024+tid*4+0] = __float2bfloat16(b.x * sc * w1.x);
    o[1024+tid*4+1] = __float2bfloat16(b.y * sc * w1.y);
    o[1024+tid*4+2] = __float2bfloat16(b.z * sc * w1.z);
    o[1024+tid*4+3] = __float2bfloat16(b.w * sc * w1.w);
}

// rms_norm(a + b) -> bf16
__global__ __launch_bounds__(256) void rmsnorm_add_kernel(const float* __restrict__ xa,
                                                          const float* __restrict__ xb,
                                                          const float* __restrict__ w,
                                                          bf16* __restrict__ out)
{
    __shared__ float sm[4];
    const int row = blockIdx.x, tid = threadIdx.x;
    const float4* ar = (const float4*)(xa + (size_t)row * HID);
    const float4* br = (const float4*)(xb + (size_t)row * HID);
    float4 a0 = ar[tid], a1 = ar[tid + 256];
    float4 b0 = br[tid], b1 = br[tid + 256];
    float4 s0, s1;
    s0.x = a0.x + b0.x; s0.y = a0.y + b0.y; s0.z = a0.z + b0.z; s0.w = a0.w + b0.w;
    s1.x = a1.x + b1.x; s1.y = a1.y + b1.y; s1.z = a1.z + b1.z; s1.w = a1.w + b1.w;
    float ss = s0.x*s0.x + s0.y*s0.y + s0.z*s0.z + s0.w*s0.w
             + s1.x*s1.x + s1.y*s1.y + s1.z*s1.z + s1.w*s1.w;
    #pragma unroll
    for (int off = 32; off; off >>= 1) ss += __shfl_down(ss, off);
    if ((tid & 63) == 0) sm[tid >> 6] = ss;
    __syncthreads();
    float sc = rsqrtf((sm[0] + sm[1] + sm[2] + sm[3]) * (1.0f / HID) + 1e-5f);
    const float4* wr = (const float4*)w;
    float4 w0 = wr[tid], w1 = wr[tid + 256];
    bf16* o = out + (size_t)row * HID;
    o[tid*4+0] = __float2bfloat16(s0.x * sc * w0.x);
    o[tid*4+1] = __float2bfloat16(s0.y * sc * w0.y);
    o[tid*4+2] = __float2bfloat16(s0.z * sc * w0.z);
    o[tid*4+3] = __float2bfloat16(s0.w * sc * w0.w);
    o[1024+tid*4+0] = __float2bfloat16(s1.x * sc * w1.x);
    o[1024+tid*4+1] = __float2bfloat16(s1.y * sc * w1.y);
    o[1024+tid*4+2] = __float2bfloat16(s1.z * sc * w1.z);
    o[1024+tid*4+3] = __float2bfloat16(s1.w * sc * w1.w);
}

// ===================== pipelined MFMA GEMM body (128 x BN, 4 waves) ========
template<int BN>
__device__ __forceinline__ void gemm_body(
    const bf16* __restrict__ A, const bf16* __restrict__ Bt,
    float* __restrict__ Cf,
    int lda, int kbeg, int klen, int ldc, int bx, int by)
{
    constexpr int NFR   = BN / 32;
    constexpr int CALLS = 4 + NFR;
    constexpr int KSRD  = 4 + NFR;
    __shared__ bf16 As[2 * 128 * 64];
    __shared__ bf16 Bs[2 * BN * 64];
    const int tid = threadIdx.x;
    const int wv = tid >> 6, ln = tid & 63;
    const int wr = wv >> 1, wc = wv & 1;
    const size_t m0 = (size_t)by * 128;
    const size_t n0 = (size_t)bx * BN;

    const int lrow = ln >> 3;
    const int lk   = (ln & 7) ^ lrow;

    const bf16* Abase = A  + (m0 + (size_t)wv*32 + lrow) * lda + kbeg + lk*8;
    const bf16* Bbase = Bt + (n0 + (size_t)wv*NFR*8 + lrow) * lda + kbeg + lk*8;
    bf16* AsW = As + wv*2048;
    bf16* BsW = Bs + wv*NFR*512;

    auto stage = [&](int p, int tk) {
        #pragma unroll
        for (int i = 0; i < 4; ++i)
            __builtin_amdgcn_global_load_lds((cg_void*)(Abase + (size_t)i*8*lda + tk),
                                             (lds_void*)(AsW + p*8192 + i*512), 16, 0, 0);
        #pragma unroll
        for (int i = 0; i < NFR; ++i)
            __builtin_amdgcn_global_load_lds((cg_void*)(Bbase + (size_t)i*8*lda + tk),
                                             (lds_void*)(BsW + p*(BN*64) + i*512), 16, 0, 0);
    };

    f32x4 acc[4][NFR] = {};
    const int nt = klen >> 6;

    stage(0, 0);
    stage(1, 64);
    asm volatile("s_waitcnt vmcnt(%0)" :: "n"(CALLS) : "memory");
    __builtin_amdgcn_sched_barrier(0);
    __builtin_amdgcn_s_barrier();

    for (int t = 0; t < nt; ++t) {
        const int p = t & 1;
        const char* Ab = (const char*)As + p * 16384;
        const char* Bb = (const char*)Bs + p * (BN * 128);

        short8 af[4][2], bfr[NFR][2];
        #pragma unroll
        for (int ks = 0; ks < 2; ++ks) {
            const int kbyte = ks*64 + (ln >> 4)*16;
            #pragma unroll
            for (int m = 0; m < 4; ++m) {
                int row = wr*64 + m*16 + (ln & 15);
                af[m][ks] = *(const short8*)(Ab + row*128 + (kbyte ^ ((row & 7) << 4)));
            }
            #pragma unroll
            for (int n = 0; n < NFR; ++n) {
                int row = wc*(BN/2) + n*16 + (ln & 15);
                bfr[n][ks] = *(const short8*)(Bb + row*128 + (kbyte ^ ((row & 7) << 4)));
            }
        }
        asm volatile("s_waitcnt lgkmcnt(%0)" :: "n"(KSRD) : "memory");
        __builtin_amdgcn_sched_barrier(0);
        __builtin_amdgcn_s_setprio(1);
        #pragma unroll
        for (int m = 0; m < 4; ++m)
            #pragma unroll
            for (int n = 0; n < NFR; ++n)
                acc[m][n] = __builtin_amdgcn_mfma_f32_16x16x32_bf16(af[m][0], bfr[n][0], acc[m][n], 0, 0, 0);
        __builtin_amdgcn_s_setprio(0);
        asm volatile("s_waitcnt lgkmcnt(0)" ::: "memory");
        __builtin_amdgcn_sched_barrier(0);
        __builtin_amdgcn_s_barrier();

        const bool more = (t + 2 < nt);
        if (more) stage(p, (t + 2) * 64);
        __builtin_amdgcn_sched_barrier(0);

        __builtin_amdgcn_s_setprio(1);
        #pragma unroll
        for (int m = 0; m < 4; ++m)
            #pragma unroll
            for (int n = 0; n < NFR; ++n)
                acc[m][n] = __builtin_amdgcn_mfma_f32_16x16x32_bf16(af[m][1], bfr[n][1], acc[m][n], 0, 0, 0);
        __builtin_amdgcn_s_setprio(0);

        if (more) { asm volatile("s_waitcnt vmcnt(%0)" :: "n"(CALLS) : "memory"); }
        else      { asm volatile("s_waitcnt vmcnt(0)" ::: "memory"); }
        __builtin_amdgcn_sched_barrier(0);
        __builtin_amdgcn_s_barrier();
    }

    const int cj = ln & 15, rj = ln >> 4;
    #pragma unroll
    for (int m = 0; m < 4; ++m) {
        #pragma unroll
        for (int j = 0; j < 4; ++j) {
            size_t row = m0 + wr*64 + m*16 + rj*4 + j;
            #pragma unroll
            for (int n = 0; n < NFR; ++n) {
                int col = (int)n0 + wc*(BN/2) + n*16 + cj;
                Cf[row * (size_t)ldc + col] = acc[m][n][j];
            }
        }
    }
}

// XCD swizzle: contiguous work chunk per XCD; M-panel (by) is the fast axis.
__device__ __forceinline__ void swz(int& bx, int& by) {
    const int nwg = gridDim.x * gridDim.y;
    int orig = blockIdx.y * gridDim.x + blockIdx.x;
    int wg = (orig & 7) * (nwg >> 3) + (orig >> 3);
    by = wg % gridDim.y;
    bx = wg / gridDim.y;
}

__global__ __launch_bounds__(256) void g_wo(const bf16* __restrict__ A,
                                            const bf16* __restrict__ Bt,
                                            float* __restrict__ C) {
    int bx, by; swz(bx, by);
    gemm_body<64>(A, Bt, C, HID, 0, HID, HID, bx, by);
}

// ===================== fused qkv GEMM + RoPE + layout (R12-proven) =========
__global__ __launch_bounds__(256) void g_qkv_fused(const bf16* __restrict__ A,
                                                   const bf16* __restrict__ Bt,
                                                   const int* __restrict__ pos_ids,
                                                   bf16* __restrict__ Qp,
                                                   bf16* __restrict__ Kp,
                                                   bf16* __restrict__ Vt)
{
    int bx, by; swz(bx, by);
    __shared__ bf16 As[2 * 128 * 64];
    __shared__ bf16 Bs[2 * 64 * 64];
    const int tid = threadIdx.x;
    const int wv = tid >> 6, ln = tid & 63;
    const int wr = wv >> 1, wc = wv & 1;
    const size_t m0 = (size_t)by * 128;
    const size_t n0 = (size_t)bx * 64;

    const int lrow = ln >> 3;
    const int lk   = (ln & 7) ^ lrow;

    const bf16* Abase = A  + (m0 + (size_t)wv*32 + lrow) * HID + lk*8;
    const bf16* Bbase = Bt + (n0 + (size_t)wv*16 + lrow) * HID + lk*8;
    bf16* AsW = As + wv*2048;
    bf16* BsW = Bs + wv*1024;

    auto stage = [&](int p, int tk) {
        #pragma unroll
        for (int i = 0; i < 4; ++i)
            __builtin_amdgcn_global_load_lds((cg_void*)(Abase + (size_t)i*8*HID + tk),
                                             (lds_void*)(AsW + p*8192 + i*512), 16, 0, 0);
        #pragma unroll
        for (int i = 0; i < 2; ++i)
            __builtin_amdgcn_global_load_lds((cg_void*)(Bbase + (size_t)i*8*HID + tk),
                                             (lds_void*)(BsW + p*4096 + i*512), 16, 0, 0);
    };

    f32x4 acc[4][2] = {};
    const int nt = HID >> 6;

    stage(0, 0);
    stage(1, 64);
    asm volatile("s_waitcnt vmcnt(6)" ::: "memory");
    __builtin_amdgcn_sched_barrier(0);
    __builtin_amdgcn_s_barrier();

    for (int t = 0; t < nt; ++t) {
        const int p = t & 1;
        const char* Ab = (const char*)As + p * 16384;
        const char* Bb = (const char*)Bs + p * 8192;

        short8 af[4][2], bfr[2][2];
        #pragma unroll
        for (int ks = 0; ks < 2; ++ks) {
            const int kbyte = ks*64 + (ln >> 4)*16;
            #pragma unroll
            for (int m = 0; m < 4; ++m) {
                int row = wr*64 + m*16 + (ln & 15);
                af[m][ks] = *(const short8*)(Ab + row*128 + (kbyte ^ ((row & 7) << 4)));
            }
            #pragma unroll
            for (int n = 0; n < 2; ++n) {
                int row = wc*16 + n*32 + (ln & 15);
                bfr[n][ks] = *(const short8*)(Bb + row*128 + (kbyte ^ ((row & 7) << 4)));
            }
        }
        asm volatile("s_waitcnt lgkmcnt(6)" ::: "memory");
        __builtin_amdgcn_sched_barrier(0);
        __builtin_amdgcn_s_setprio(1);
        #pragma unroll
        for (int m = 0; m < 4; ++m)
            #pragma unroll
            for (int n = 0; n < 2; ++n)
                acc[m][n] = __builtin_amdgcn_mfma_f32_16x16x32_bf16(af[m][0], bfr[n][0], acc[m][n], 0, 0, 0);
        __builtin_amdgcn_s_setprio(0);
        asm volatile("s_waitcnt lgkmcnt(0)" ::: "memory");
        __builtin_amdgcn_sched_barrier(0);
        __builtin_amdgcn_s_barrier();

        const bool more = (t + 2 < nt);
        if (more) stage(p, (t + 2) * 64);
        __builtin_amdgcn_sched_barrier(0);

        __builtin_amdgcn_s_setprio(1);
        #pragma unroll
        for (int m = 0; m < 4; ++m)
            #pragma unroll
            for (int n = 0; n < 2; ++n)
                acc[m][n] = __builtin_amdgcn_mfma_f32_16x16x32_bf16(af[m][1], bfr[n][1], acc[m][n], 0, 0, 0);
        __builtin_amdgcn_s_setprio(0);

        if (more) { asm volatile("s_waitcnt vmcnt(6)" ::: "memory"); }
        else      { asm volatile("s_waitcnt vmcnt(0)" ::: "memory"); }
        __builtin_amdgcn_sched_barrier(0);
        __builtin_amdgcn_s_barrier();
    }

    const int rj = ln >> 4;
    const int jj = wc*16 + (ln & 15);
    if (bx < 40) {
        const float invf = exp2f(-(float)jj * 0.5916115177913804f);
        bf16* dst = (bx < 32) ? Qp : Kp;
        const int hh = (bx < 32) ? bx : (bx - 32);
        const int nh = (bx < 32) ? 32 : 8;
        #pragma unroll
        for (int m = 0; m < 4; ++m) {
            #pragma unroll
            for (int j = 0; j < 4; ++j) {
                int t = (int)m0 + wr*64 + m*16 + rj*4 + j;
                int s = t & 1023, b = t >> 10;
                float ang = (float)pos_ids[t] * invf;
                float c, sn;
                sincosf(ang, &sn, &c);
                float x1 = acc[m][0][j], x2 = acc[m][1][j];
                size_t base = ((size_t)(b*nh + hh)*1024 + s)*64;
                dst[base + jj]      = __float2bfloat16(x1*c - x2*sn);
                dst[base + jj + 32] = __float2bfloat16(x2*c + x1*sn);
            }
        }
    } else {
        const int hv = bx - 40;
        #pragma unroll
        for (int m = 0; m < 4; ++m) {
            int t0 = (int)m0 + wr*64 + m*16 + rj*4;
            int s0 = t0 & 1023, b = t0 >> 10;
            #pragma unroll
            for (int n = 0; n < 2; ++n) {
                int d = jj + n*32;
                us4 pk;
                #pragma unroll
                for (int j = 0; j < 4; ++j)
                    pk[j] = __bfloat16_as_ushort(__float2bfloat16(acc[m][n][j]));
                *(us4*)(Vt + ((size_t)(b*8 + hv)*64 + d)*1024 + s0) = pk;
            }
        }
    }
}

// ===================== 256x256 2-phase GEMM body (R11-proven, g_down) ======
template<int EPI>
__device__ __forceinline__ void gemm256_body(
    const bf16* __restrict__ A, const bf16* __restrict__ Bt,
    float* __restrict__ Cf, bf16* __restrict__ Cb,
    int lda, int kbeg, int klen, int ldc, int bx, int by)
{
    __shared__ bf16 As[2 * 256 * 64];
    __shared__ bf16 Bs[2 * 256 * 64];
    const int tid = threadIdx.x;
    const int wv = tid >> 6, ln = tid & 63;
    const int wr = wv >> 2, wc = wv & 3;
    const size_t m0 = (size_t)by * 256;
    const size_t n0 = (size_t)bx * 256;

    const int lrow = ln >> 3;
    const int lk   = (ln & 7) ^ lrow;

    const bf16* Abase = A  + (m0 + (size_t)wv*32 + lrow) * lda + kbeg + lk*8;
    const bf16* Bbase = Bt + (n0 + (size_t)wv*32 + lrow) * lda + kbeg + lk*8;
    bf16* AsW = As + wv*2048;
    bf16* BsW = Bs + wv*2048;

    auto stage = [&](int p, int tk) {
        #pragma unroll
        for (int i = 0; i < 4; ++i)
            __builtin_amdgcn_global_load_lds((cg_void*)(Abase + (size_t)i*8*lda + tk),
                                             (lds_void*)(AsW + p*16384 + i*512), 16, 0, 0);
        #pragma unroll
        for (int i = 0; i < 4; ++i)
            __builtin_amdgcn_global_load_lds((cg_void*)(Bbase + (size_t)i*8*lda + tk),
                                             (lds_void*)(BsW + p*16384 + i*512), 16, 0, 0);
    };

    f32x4 acc[8][4] = {};
    const int nt = klen >> 6;

    stage(0, 0);
    stage(1, 64);
    asm volatile("s_waitcnt vmcnt(8)" ::: "memory");
    __builtin_amdgcn_sched_barrier(0);
    __builtin_amdgcn_s_barrier();

    for (int t = 0; t < nt; ++t) {
        const int p = t & 1;
        const char* Ab = (const char*)As + p * 32768;
        const char* Bb = (const char*)Bs + p * 32768;

        short8 af0[8], bf0[4], af1[8], bf1[4];
        {
            const int kbyte = (ln >> 4) * 16;
            #pragma unroll
            for (int m = 0; m < 8; ++m) {
                int row = wr*128 + m*16 + (ln & 15);
                af0[m] = *(const short8*)(Ab + row*128 + (kbyte ^ ((row & 7) << 4)));
            }
            #pragma unroll
            for (int n = 0; n < 4; ++n) {
                int row = wc*64 + n*16 + (ln & 15);
                bf0[n] = *(const short8*)(Bb + row*128 + (kbyte ^ ((row & 7) << 4)));
            }
        }
        {
            const int kbyte = 64 + (ln >> 4) * 16;
            #pragma unroll
            for (int m = 0; m < 8; ++m) {
                int row = wr*128 + m*16 + (ln & 15);
                af1[m] = *(const short8*)(Ab + row*128 + (kbyte ^ ((row & 7) << 4)));
            }
            #pragma unroll
            for (int n = 0; n < 4; ++n) {
                int row = wc*64 + n*16 + (ln & 15);
                bf1[n] = *(const short8*)(Bb + row*128 + (kbyte ^ ((row & 7) << 4)));
            }
        }
        asm volatile("s_waitcnt lgkmcnt(12)" ::: "memory");
        __builtin_amdgcn_sched_barrier(0);
        __builtin_amdgcn_s_setprio(1);
        #pragma unroll
        for (int m = 0; m < 8; ++m)
            #pragma unroll
            for (int n = 0; n < 4; ++n)
                acc[m][n] = __builtin_amdgcn_mfma_f32_16x16x32_bf16(af0[m], bf0[n], acc[m][n], 0, 0, 0);
        __builtin_amdgcn_s_setprio(0);
        asm volatile("s_waitcnt lgkmcnt(0)" ::: "memory");
        __builtin_amdgcn_sched_barrier(0);
        __builtin_amdgcn_s_barrier();

        const bool more = (t + 2 < nt);
        if (more) stage(p, (t + 2) * 64);
        __builtin_amdgcn_sched_barrier(0);

        __builtin_amdgcn_s_setprio(1);
        #pragma unroll
        for (int m = 0; m < 8; ++m)
            #pragma unroll
            for (int n = 0; n < 4; ++n)
                acc[m][n] = __builtin_amdgcn_mfma_f32_16x16x32_bf16(af1[m], bf1[n], acc[m][n], 0, 0, 0);
        __builtin_amdgcn_s_setprio(0);

        if (more) { asm volatile("s_waitcnt vmcnt(8)" ::: "memory"); }
        else      { asm volatile("s_waitcnt vmcnt(0)" ::: "memory"); }
        __builtin_amdgcn_sched_barrier(0);
        __builtin_amdgcn_s_barrier();
    }

    const int cj = ln & 15, rj = ln >> 4;
    if constexpr (EPI == 4) {
        const int slab = (int)(n0 >> 6) + wc;
        #pragma unroll
        for (int m = 0; m < 8; ++m) {
            #pragma unroll
            for (int j = 0; j < 4; ++j) {
                size_t row = m0 + wr*128 + m*16 + rj*4 + j;
                #pragma unroll
                for (int n = 0; n < 2; ++n) {
                    int col = slab*32 + n*16 + cj;
                    float g = acc[m][n][j];
                    float u = acc[m][n+2][j];
                    Cb[row * (size_t)ldc + col] =
                        __float2bfloat16(g / (1.0f + __expf(-g)) * u);
                }
            }
        }
    } else {
        #pragma unroll
        for (int m = 0; m < 8; ++m) {
            #pragma unroll
            for (int j = 0; j < 4; ++j) {
                size_t row = m0 + wr*128 + m*16 + rj*4 + j;
                #pragma unroll
                for (int n = 0; n < 4; ++n) {
                    int col = (int)n0 + wc*64 + n*16 + cj;
                    unsafeAtomicAdd(&Cf[row * (size_t)ldc + col], acc[m][n][j]);
                }
            }
        }
    }
}

// down-proj: 256x256 tile, split-K=8 (z), atomicAdd into d_out (holds attn_out)
__global__ __launch_bounds__(512, 2) void g_down(const bf16* __restrict__ A,
                                                 const bf16* __restrict__ Bt,
                                                 float* __restrict__ C)
{
    const int nwg = gridDim.x * gridDim.y;
    int orig = blockIdx.y * gridDim.x + blockIdx.x;
    int wg = (orig & 7) * (nwg >> 3) + (orig >> 3);
    const int by = wg % gridDim.y, bx = wg / gridDim.y;
    gemm256_body<5>(A, Bt, C, nullptr, FFN_DIM, blockIdx.z * 1024, 1024, HID, bx, by);
}

// ===================== gateup: 256x256 8-phase GEMM (m201-style) ===========
// 8 waves (2M x 4N), wave tile 128x64, BK=64, 2x64KB dbuf LDS.
// Iteration computes K-tiles (t, t+1). Phase (mh,nh) = one C-quadrant:
// fragment reuse (af reload at mh switch; all 4 bfr live) -> 24 ds_read/tile.
// Stage slots (2 gload_lds calls each), operand-granular hazards:
//   ph0,1: A(t+1)->buf1 (buf1 A free since prev ph6)
//   ph2,3: B(t+2)->buf0 (buf0 B fully read by ph1)
//   ph4,5: A(t+2)->buf0 (buf0 A fully read by ph2)
//   ph6,7: B(t+3)->buf1 (buf1 B fully read by ph5)
// vmcnt(4) mid (drains B(t+1),A(t+1)) and end (drains B(t+2),A(t+2)).
#define RD_A(Ab, MH)                                                          \
    { const int rbase = wr*128 + (MH)*64 + (ln & 15);                         \
      _Pragma("unroll")                                                       \
      for (int m = 0; m < 4; ++m) {                                           \
        int row = rbase + m*16;                                               \
        _Pragma("unroll")                                                     \
        for (int ks = 0; ks < 2; ++ks)                                        \
          af[m][ks] = *(const short8*)((Ab) + row*128 +                       \
                        ((ks*64 + (ln >> 4)*16) ^ ((row & 7) << 4)));         \
      } }
#define RD_B(Bb, NH)                                                          \
    { _Pragma("unroll")                                                       \
      for (int n = 0; n < 2; ++n) {                                           \
        int row = wc*64 + (NH)*32 + n*16 + (ln & 15);                         \
        _Pragma("unroll")                                                     \
        for (int ks = 0; ks < 2; ++ks)                                        \
          bfr[(NH)*2+n][ks] = *(const short8*)((Bb) + row*128 +               \
                        ((ks*64 + (ln >> 4)*16) ^ ((row & 7) << 4)));         \
      } }
#define MM(MH, NH)                                                            \
    __builtin_amdgcn_s_barrier();                                             \
    asm volatile("s_waitcnt lgkmcnt(0)" ::: "memory");                        \
    __builtin_amdgcn_sched_barrier(0);                                        \
    __builtin_amdgcn_s_setprio(1);                                            \
    _Pragma("unroll")                                                         \
    for (int ks = 0; ks < 2; ++ks)                                            \
      _Pragma("unroll")                                                       \
      for (int m = 0; m < 4; ++m)                                             \
        _Pragma("unroll")                                                     \
        for (int n = 0; n < 2; ++n)                                           \
          acc[(MH)*4+m][(NH)*2+n] = __builtin_amdgcn_mfma_f32_16x16x32_bf16(  \
              af[m][ks], bfr[(NH)*2+n][ks], acc[(MH)*4+m][(NH)*2+n], 0,0,0);  \
    __builtin_amdgcn_s_setprio(0);                                            \
    __builtin_amdgcn_sched_barrier(0);                                        \
    __builtin_amdgcn_s_barrier();

__global__ __launch_bounds__(512, 2) void g_gateup(const bf16* __restrict__ A,
                                                   const bf16* __restrict__ Bt,
                                                   bf16* __restrict__ C)
{
    __shared__ bf16 As[2 * 256 * 64];
    __shared__ bf16 Bs[2 * 256 * 64];
    const int tid = threadIdx.x;
    const int wv = tid >> 6, ln = tid & 63;
    const int wr = wv >> 2, wc = wv & 3;
    const int nwg = gridDim.x * gridDim.y;
    int orig = blockIdx.y * gridDim.x + blockIdx.x;
    int wg = (orig & 7) * (nwg >> 3) + (orig >> 3);
    const int by = wg % gridDim.y, bx = wg / gridDim.y;
    const size_t m0 = (size_t)by * 256;
    const size_t n0 = (size_t)bx * 256;

    const int lrow = ln >> 3;
    const int lk   = (ln & 7) ^ lrow;

    const bf16* Abase = A  + (m0 + (size_t)wv*32 + lrow) * HID + lk*8;
    const bf16* Bbase = Bt + (n0 + (size_t)wv*32 + lrow) * HID + lk*8;
    bf16* AsW = As + wv*2048;
    bf16* BsW = Bs + wv*2048;

    auto stA = [&](int p, int tk, int c) {
        #pragma unroll
        for (int u = 0; u < 2; ++u) {
            int i = 2*c + u;
            __builtin_amdgcn_global_load_lds((cg_void*)(Abase + (size_t)i*8*HID + tk),
                                             (lds_void*)(AsW + p*16384 + i*512), 16, 0, 0);
        }
    };
    auto stB = [&](int p, int tk, int c) {
        #pragma unroll
        for (int u = 0; u < 2; ++u) {
            int i = 2*c + u;
            __builtin_amdgcn_global_load_lds((cg_void*)(Bbase + (size_t)i*8*HID + tk),
                                             (lds_void*)(BsW + p*16384 + i*512), 16, 0, 0);
        }
    };

    f32x4 acc[8][4] = {};
    constexpr int nt = HID / 64;   // 32 (even)

    // prologue: B(0),A(0) -> buf0; B(1) -> buf1. Drain B0,A0; B1 in flight.
    stB(0, 0, 0); stB(0, 0, 1);
    stA(0, 0, 0); stA(0, 0, 1);
    stB(1, 64, 0); stB(1, 64, 1);
    asm volatile("s_waitcnt vmcnt(4)" ::: "memory");
    __builtin_amdgcn_sched_barrier(0);
    __builtin_amdgcn_s_barrier();

    short8 af[4][2], bfr[4][2];
    const char* Ab0 = (const char*)As;
    const char* Bb0 = (const char*)Bs;
    const char* Ab1 = (const char*)As + 32768;
    const char* Bb1 = (const char*)Bs + 32768;

    for (int i = 0; i < nt/2; ++i) {
        const int t = 2*i;
        const bool s2 = (t + 2 < nt);
        const bool s3 = (t + 3 < nt);
        // ---- tile t (buf0) ----
        RD_A(Ab0, 0) RD_B(Bb0, 0)
        stA(1, (t+1)*64, 0);
        __builtin_amdgcn_sched_barrier(0);
        MM(0, 0)
        RD_B(Bb0, 1)
        stA(1, (t+1)*64, 1);
        __builtin_amdgcn_sched_barrier(0);
        MM(0, 1)
        RD_A(Ab0, 1)
        if (s2) stB(0, (t+2)*64, 0);
        __builtin_amdgcn_sched_barrier(0);
        MM(1, 0)
        if (s2) stB(0, (t+2)*64, 1);
        __builtin_amdgcn_sched_barrier(0);
        MM(1, 1)
        // mid wait: B(t+1),A(t+1) landed
        if (s2) { asm volatile("s_waitcnt vmcnt(4)" ::: "memory"); }
        else    { asm volatile("s_waitcnt vmcnt(0)" ::: "memory"); }
        __builtin_amdgcn_sched_barrier(0);
        __builtin_amdgcn_s_barrier();
        // ---- tile t+1 (buf1) ----
        RD_A(Ab1, 0) RD_B(Bb1, 0)
        if (s2) stA(0, (t+2)*64, 0);
        __builtin_amdgcn_sched_barrier(0);
        MM(0, 0)
        RD_B(Bb1, 1)
        if (s2) stA(0, (t+2)*64, 1);
        __builtin_amdgcn_sched_barrier(0);
        MM(0, 1)
        RD_A(Ab1, 1)
        if (s3) stB(1, (t+3)*64, 0);
        __builtin_amdgcn_sched_barrier(0);
        MM(1, 0)
        if (s3) stB(1, (t+3)*64, 1);
        __builtin_amdgcn_sched_barrier(0);
        MM(1, 1)
        // end wait: B(t+2),A(t+2) landed (next iteration reads buf0)
        if (s2) {
            asm volatile("s_waitcnt vmcnt(4)" ::: "memory");
            __builtin_amdgcn_sched_barrier(0);
            __builtin_amdgcn_s_barrier();
        }
    }

    // epilogue: interleaved gate/up slab -> silu(g)*u bf16
    const int cj = ln & 15, rj = ln >> 4;
    const int slab = (int)(n0 >> 6) + wc;
    #pragma unroll
    for (int m = 0; m < 8; ++m) {
        #pragma unroll
        for (int j = 0; j < 4; ++j) {
            size_t row = m0 + wr*128 + m*16 + rj*4 + j;
            #pragma unroll
            for (int n = 0; n < 2; ++n) {
                int col = slab*32 + n*16 + cj;
                float g = acc[m][n][j];
                float u = acc[m][n+2][j];
                C[row * (size_t)FFN_DIM + col] =
                    __float2bfloat16(g / (1.0f + __expf(-g)) * u);
            }
        }
    }
}

// ===================== MFMA flash attention (bf16, causal, GQA) ============
__global__ __launch_bounds__(256) void attn_mfma(const bf16* __restrict__ Qp,
                                                 const bf16* __restrict__ Kp,
                                                 const bf16* __restrict__ Vt,
                                                 bf16* __restrict__ ctx)
{
    __shared__ bf16 Ks[128 * 64];
    __shared__ bf16 Vs[64 * 128];
    __shared__ bf16 Ps[4 * 32 * 128];
    const int tid = threadIdx.x;
    const int w = tid >> 6, ln = tid & 63;
    const int qt = blockIdx.x, h = blockIdx.y, b = blockIdx.z;
    const int hk = h >> 2;
    const int q0 = qt * 128;

    const bf16* qsec = Qp + ((size_t)(b*32 + h)*1024 + q0 + w*32)*64;
    const bf16* ksec = Kp + ((size_t)(b*8 + hk)*1024)*64;
    const bf16* vsec = Vt + ((size_t)(b*8 + hk))*64*1024;

    short8 qf[2][2];
    #pragma unroll
    for (int f = 0; f < 2; ++f)
        #pragma unroll
        for (int kc = 0; kc < 2; ++kc)
            qf[f][kc] = *(const short8*)(qsec + (size_t)(f*16 + (ln & 15))*64 + kc*32 + (ln >> 4)*8);

    f32x4 acc_o[2][4] = {};
    f32x4 m[2], l[2];
    #pragma unroll
    for (int f = 0; f < 2; ++f)
        #pragma unroll
        for (int j = 0; j < 4; ++j) { m[f][j] = -1e30f; l[f][j] = 0.0f; }

    const int lrow = ln >> 3;
    const int lkk  = (ln & 7) ^ lrow;
    char* PsW = (char*)Ps + w * 8192;

    const int ntiles = qt + 1;
    for (int kt = 0; kt < ntiles; ++kt) {
        const int kv0 = kt * 128;
        {
            const bf16* kbase = ksec + (size_t)(kv0 + w*32 + lrow)*64 + lkk*8;
            bf16* KsW = Ks + w*2048;
            #pragma unroll
            for (int i = 0; i < 4; ++i)
                __builtin_amdgcn_global_load_lds((cg_void*)(kbase + (size_t)i*8*64),
                                                 (lds_void*)(KsW + i*512), 16, 0, 0);
        }
        {
            bf16* VsW = Vs + w*2048;
            #pragma unroll
            for (int i = 0; i < 4; ++i) {
                int d = w*16 + i*4 + (ln >> 4);
                __builtin_amdgcn_global_load_lds(
                    (cg_void*)(vsec + (size_t)d*1024 + kv0 + (((ln & 15) ^ (d & 7))*8)),
                    (lds_void*)(VsW + i*512), 16, 0, 0);
            }
        }
        __syncthreads();

        f32x4 acc_s[2][8] = {};
        #pragma unroll
        for (int c = 0; c < 8; ++c) {
            int kvr = c*16 + (ln & 15);
            const char* krow = (const char*)Ks + kvr*128;
            short8 kf0 = *(const short8*)(krow + (((ln >> 4)*16)      ^ ((kvr & 7) << 4)));
            short8 kf1 = *(const short8*)(krow + ((64 + (ln >> 4)*16) ^ ((kvr & 7) << 4)));
            #pragma unroll
            for (int f = 0; f < 2; ++f) {
                acc_s[f][c] = __builtin_amdgcn_mfma_f32_16x16x32_bf16(qf[f][0], kf0, acc_s[f][c], 0, 0, 0);
                acc_s[f][c] = __builtin_amdgcn_mfma_f32_16x16x32_bf16(qf[f][1], kf1, acc_s[f][c], 0, 0, 0);
            }
        }

        const bool diag = (kt == qt);
        f32x4 vmax[2];
        #pragma unroll
        for (int f = 0; f < 2; ++f)
            #pragma unroll
            for (int j = 0; j < 4; ++j) vmax[f][j] = -1e30f;
        #pragma unroll
        for (int f = 0; f < 2; ++f) {
            #pragma unroll
            for (int c = 0; c < 8; ++c) {
                f32x4 t = acc_s[f][c] * 0.125f;
                if (diag) {
                    int kv = kv0 + c*16 + (ln & 15);
                    int qg = q0 + w*32 + f*16 + (ln >> 4)*4;
                    #pragma unroll
                    for (int j = 0; j < 4; ++j)
                        if (kv > qg + j) t[j] = -1e30f;
                }
                acc_s[f][c] = t;
                #pragma unroll
                for (int j = 0; j < 4; ++j) vmax[f][j] = fmaxf(vmax[f][j], t[j]);
            }
            #pragma unroll
            for (int mk = 1; mk <= 8; mk <<= 1)
                #pragma unroll
                for (int j = 0; j < 4; ++j)
                    vmax[f][j] = fmaxf(vmax[f][j], __shfl_xor(vmax[f][j], mk));
        }

        #pragma unroll
        for (int f = 0; f < 2; ++f) {
            f32x4 r;
            #pragma unroll
            for (int j = 0; j < 4; ++j) {
                float mn = fmaxf(m[f][j], vmax[f][j]);
                r[j] = __expf(m[f][j] - mn);
                m[f][j] = mn;
                l[f][j] *= r[j];
            }
            #pragma unroll
            for (int df = 0; df < 4; ++df)
                #pragma unroll
                for (int j = 0; j < 4; ++j) acc_o[f][df][j] *= r[j];
        }

        f32x4 rs[2] = {};
        #pragma unroll
        for (int f = 0; f < 2; ++f) {
            #pragma unroll
            for (int c = 0; c < 8; ++c) {
                #pragma unroll
                for (int j = 0; j < 4; ++j) {
                    float p = __expf(acc_s[f][c][j] - m[f][j]);
                    rs[f][j] += p;
                    int qloc = f*16 + (ln >> 4)*4 + j;
                    int kvb  = (c*16 + (ln & 15))*2;
                    *(bf16*)(PsW + qloc*256 + (kvb ^ ((qloc & 7) << 4))) = __float2bfloat16(p);
                }
            }
            #pragma unroll
            for (int mk = 1; mk <= 8; mk <<= 1)
                #pragma unroll
                for (int j = 0; j < 4; ++j)
                    rs[f][j] += __shfl_xor(rs[f][j], mk);
            #pragma unroll
            for (int j = 0; j < 4; ++j) l[f][j] += rs[f][j];
        }

        #pragma unroll
        for (int kc = 0; kc < 4; ++kc) {
            short8 pa[2];
            #pragma unroll
            for (int f = 0; f < 2; ++f) {
                int qloc = f*16 + (ln & 15);
                pa[f] = *(const short8*)(PsW + qloc*256 + ((kc*64 + (ln >> 4)*16) ^ ((qloc & 7) << 4)));
            }
            #pragma unroll
            for (int df = 0; df < 4; ++df) {
                int dl = df*16 + (ln & 15);
                short8 vfr = *(const short8*)((const char*)Vs + dl*256 + ((kc*64 + (ln >> 4)*16) ^ ((dl & 7) << 4)));
                #pragma unroll
                for (int f = 0; f < 2; ++f)
                    acc_o[f][df] = __builtin_amdgcn_mfma_f32_16x16x32_bf16(pa[f], vfr, acc_o[f][df], 0, 0, 0);
            }
        }
        __syncthreads();
    }

    #pragma unroll
    for (int f = 0; f < 2; ++f) {
        f32x4 inv;
        #pragma unroll
        for (int j = 0; j < 4; ++j) inv[j] = 1.0f / l[f][j];
        #pragma unroll
        for (int df = 0; df < 4; ++df) {
            #pragma unroll
            for (int j = 0; j < 4; ++j) {
                int q = q0 + w*32 + f*16 + (ln >> 4)*4 + j;
                int d = df*16 + (ln & 15);
                ctx[((size_t)b*1024 + q)*HID + h*64 + d] = __float2bfloat16(acc_o[f][df][j] * inv[j]);
            }
        }
    }
}

// ===================== launch ==============================================
extern "C" void kernel_launch(void* const* d_in, const int* in_sizes, int n_in,
                              void* d_out, int out_size, void* d_ws, size_t ws_size,
                              hipStream_t stream)
{
    const float* hidden = (const float*)d_in[0];
    const float* wq = (const float*)d_in[2];
    const float* wk = (const float*)d_in[3];
    const float* wv = (const float*)d_in[4];
    const float* wo = (const float*)d_in[5];
    const float* n1 = (const float*)d_in[6];
    const float* n2 = (const float*)d_in[7];
    const float* wg = (const float*)d_in[8];
    const float* wu = (const float*)d_in[9];
    const float* wd = (const float*)d_in[10];
    const int*  pos = (const int*)d_in[11];
    float* out = (float*)d_out;
    char* ws = (char*)d_ws;

    // workspace layout (byte offsets)
    bf16* wgu_t  = (bf16*)(ws + 0);           // [16384][2048] interleaved gate/up
    bf16* wd_t   = (bf16*)(ws + 67108864);    // [2048][8192]
    bf16* wqkv_t = (bf16*)(ws + 100663296);   // [3072][2048]
    bf16* wo_t   = (bf16*)(ws + 113246208);   // [2048][2048]
    bf16* normed = (bf16*)(ws + 121634816);   // [2048][2048]
    bf16* Qp     = (bf16*)(ws + 130023424);   // [64][1024][64]
    bf16* ctx    = (bf16*)(ws + 155189248);   // [2048][2048]
    bf16* hb     = (bf16*)(ws + 130023424);   // [2048][8192] aliases Qp+ctx (dead in FFN)
    bf16* Kp     = (bf16*)(ws + 163577856);   // [16][1024][64]
    bf16* Vt     = (bf16*)(ws + 165675008);   // [16][64][1024]

    // weight casts (vectorized 8B writes)
    cast_transpose<<<dim3(32, 32), 256, 0, stream>>>(wq, wqkv_t, 2048, 2048);
    cast_transpose<<<dim3(8, 32),  256, 0, stream>>>(wk, wqkv_t + 4194304, 2048, 512);
    cast_transpose<<<dim3(8, 32),  256, 0, stream>>>(wv, wqkv_t + 5242880, 2048, 512);
    cast_transpose<<<dim3(32, 32), 256, 0, stream>>>(wo, wo_t, 2048, 2048);
    cast_ilv<<<dim3(128, 32), 256, 0, stream>>>(wg, wgu_t, FFN_DIM, 0);
    cast_ilv<<<dim3(128, 32), 256, 0, stream>>>(wu, wgu_t, FFN_DIM, 1);
    cast_transpose<<<dim3(32, 128),256, 0, stream>>>(wd, wd_t, 8192, 2048);

    // 1. normed = rms_norm(hidden)
    rmsnorm_kernel<<<T_TOK, 256, 0, stream>>>(hidden, n1, normed);
    // 2-3. fused qkv GEMM + RoPE + head-major/V-transpose layout
    g_qkv_fused<<<dim3(QKV_N/64, T_TOK/128), 256, 0, stream>>>(
        normed, wqkv_t, pos, Qp, Kp, Vt);
    // 4. MFMA flash attention -> ctx (bf16)
    attn_mfma<<<dim3(8, NHEADS, 2), 256, 0, stream>>>(Qp, Kp, Vt, ctx);
    // 5. attn_out = ctx @ wo -> d_out (f32)
    g_wo<<<dim3(HID/64, T_TOK/128), 256, 0, stream>>>(ctx, wo_t, out);
    // 6. normed2 = rms_norm(attn_out + hidden)
    rmsnorm_add_kernel<<<T_TOK, 256, 0, stream>>>(out, hidden, n2, normed);
    // 7. hb = silu(normed @ wg) * (normed @ wu)  -- 256x256 8-phase GEMM
    g_gateup<<<dim3(16384/256, T_TOK/256), 512, 0, stream>>>(normed, wgu_t, hb);
    // 8. d_out += hb @ wd  -- 256x256 2-phase, split-K=8, atomic f32 add
    g_down<<<dim3(HID/256, T_TOK/256, 8), 512, 0, stream>>>(hb, wd_t, out);
}

// Round 14
// 535.437 us; speedup vs baseline: 1.0671x; 1.0671x over previous
//
#include <hip/hip_runtime.h>
#include <hip/hip_bf16.h>
#include <cstddef>
#include <cstdint>

#define T_TOK   2048
#define HID     2048
#define NHEADS  32
#define NKV     8
#define HDIM    64
#define FFN_DIM 8192
#define QKV_N   3072

typedef __hip_bfloat16 bf16;
typedef __attribute__((ext_vector_type(8))) short short8;
typedef __attribute__((ext_vector_type(4))) float f32x4;
typedef __attribute__((ext_vector_type(4))) unsigned short us4;

typedef __attribute__((address_space(1))) const void cg_void;
typedef __attribute__((address_space(3))) void lds_void;

// ========== cast + transpose: W[K][N] f32 -> Wt[N][K] bf16 (vectorized) ====
__global__ __launch_bounds__(256) void cast_transpose(const float* __restrict__ in,
                                                      bf16* __restrict__ out,
                                                      int K, int N)
{
    __shared__ bf16 t[64][68];
    const int n0 = blockIdx.x * 64, k0 = blockIdx.y * 64;
    const int g = threadIdx.x & 15, r = threadIdx.x >> 4;
    #pragma unroll
    for (int p = 0; p < 4; ++p) {
        int kr = r + p*16;
        float4 v = *(const float4*)(in + (size_t)(k0 + kr) * N + n0 + g*4);
        t[kr][g*4+0] = __float2bfloat16(v.x);
        t[kr][g*4+1] = __float2bfloat16(v.y);
        t[kr][g*4+2] = __float2bfloat16(v.z);
        t[kr][g*4+3] = __float2bfloat16(v.w);
    }
    __syncthreads();
    #pragma unroll
    for (int p = 0; p < 4; ++p) {
        int nr = r + p*16;
        us4 pk;
        #pragma unroll
        for (int i = 0; i < 4; ++i)
            pk[i] = __bfloat16_as_ushort(t[g*4+i][nr]);
        *(us4*)(out + (size_t)(n0 + nr) * K + k0 + g*4) = pk;
    }
}

// interleaved variant for gate/up fusion: col n -> row (n/32)*64 + is_up*32 + n%32
__global__ __launch_bounds__(256) void cast_ilv(const float* __restrict__ in,
                                                bf16* __restrict__ out,
                                                int N, int is_up)
{
    __shared__ bf16 t[64][68];
    const int n0 = blockIdx.x * 64, k0 = blockIdx.y * 64;
    const int g = threadIdx.x & 15, r = threadIdx.x >> 4;
    #pragma unroll
    for (int p = 0; p < 4; ++p) {
        int kr = r + p*16;
        float4 v = *(const float4*)(in + (size_t)(k0 + kr) * N + n0 + g*4);
        t[kr][g*4+0] = __float2bfloat16(v.x);
        t[kr][g*4+1] = __float2bfloat16(v.y);
        t[kr][g*4+2] = __float2bfloat16(v.z);
        t[kr][g*4+3] = __float2bfloat16(v.w);
    }
    __syncthreads();
    #pragma unroll
    for (int p = 0; p < 4; ++p) {
        int nr = r + p*16;
        int n = n0 + nr;
        int rr = ((n >> 5) << 6) + (is_up << 5) + (n & 31);
        us4 pk;
        #pragma unroll
        for (int i = 0; i < 4; ++i)
            pk[i] = __bfloat16_as_ushort(t[g*4+i][nr]);
        *(us4*)(out + (size_t)rr * HID + k0 + g*4) = pk;
    }
}

// ===================== RMSNorm (f32 in -> bf16 out) ========================
__global__ __launch_bounds__(256) void rmsnorm_kernel(const float* __restrict__ x,
                                                      const float* __restrict__ w,
                                                      bf16* __restrict__ out)
{
    __shared__ float sm[4];
    const int row = blockIdx.x, tid = threadIdx.x;
    const float4* xr = (const float4*)(x + (size_t)row * HID);
    float4 a = xr[tid], b = xr[tid + 256];
    float ss = a.x*a.x + a.y*a.y + a.z*a.z + a.w*a.w
             + b.x*b.x + b.y*b.y + b.z*b.z + b.w*b.w;
    #pragma unroll
    for (int off = 32; off; off >>= 1) ss += __shfl_down(ss, off);
    if ((tid & 63) == 0) sm[tid >> 6] = ss;
    __syncthreads();
    float sc = rsqrtf((sm[0] + sm[1] + sm[2] + sm[3]) * (1.0f / HID) + 1e-5f);
    const float4* wr = (const float4*)w;
    float4 w0 = wr[tid], w1 = wr[tid + 256];
    bf16* o = out + (size_t)row * HID;
    o[tid*4+0] = __float2bfloat16(a.x * sc * w0.x);
    o[tid*4+1] = __float2bfloat16(a.y * sc * w0.y);
    o[tid*4+2] = __float2bfloat16(a.z * sc * w0.z);
    o[tid*4+3] = __float2bfloat16(a.w * sc * w0.w);
    o[1024+tid*4+0] = __float2bfloat16(b.x * sc * w1.x);
    o[1024+tid*4+1] = __float2bfloat16(b.y * sc * w1.y);
    o[1024+tid*4+2] = __float2bfloat16(b.z * sc * w1.z);
    o[1024+tid*4+3] = __float2bfloat16(b.w * sc * w1.w);
}

// rms_norm(a + b) -> bf16
__global__ __launch_bounds__(256) void rmsnorm_add_kernel(const float* __restrict__ xa,
                                                          const float* __restrict__ xb,
                                                          const float* __restrict__ w,
                                                          bf16* __restrict__ out)
{
    __shared__ float sm[4];
    const int row = blockIdx.x, tid = threadIdx.x;
    const float4* ar = (const float4*)(xa + (size_t)row * HID);
    const float4* br = (const float4*)(xb + (size_t)row * HID);
    float4 a0 = ar[tid], a1 = ar[tid + 256];
    float4 b0 = br[tid], b1 = br[tid + 256];
    float4 s0, s1;
    s0.x = a0.x + b0.x; s0.y = a0.y + b0.y; s0.z = a0.z + b0.z; s0.w = a0.w + b0.w;
    s1.x = a1.x + b1.x; s1.y = a1.y + b1.y; s1.z = a1.z + b1.z; s1.w = a1.w + b1.w;
    float ss = s0.x*s0.x + s0.y*s0.y + s0.z*s0.z + s0.w*s0.w
             + s1.x*s1.x + s1.y*s1.y + s1.z*s1.z + s1.w*s1.w;
    #pragma unroll
    for (int off = 32; off; off >>= 1) ss += __shfl_down(ss, off);
    if ((tid & 63) == 0) sm[tid >> 6] = ss;
    __syncthreads();
    float sc = rsqrtf((sm[0] + sm[1] + sm[2] + sm[3]) * (1.0f / HID) + 1e-5f);
    const float4* wr = (const float4*)w;
    float4 w0 = wr[tid], w1 = wr[tid + 256];
    bf16* o = out + (size_t)row * HID;
    o[tid*4+0] = __float2bfloat16(s0.x * sc * w0.x);
    o[tid*4+1] = __float2bfloat16(s0.y * sc * w0.y);
    o[tid*4+2] = __float2bfloat16(s0.z * sc * w0.z);
    o[tid*4+3] = __float2bfloat16(s0.w * sc * w0.w);
    o[1024+tid*4+0] = __float2bfloat16(s1.x * sc * w1.x);
    o[1024+tid*4+1] = __float2bfloat16(s1.y * sc * w1.y);
    o[1024+tid*4+2] = __float2bfloat16(s1.z * sc * w1.z);
    o[1024+tid*4+3] = __float2bfloat16(s1.w * sc * w1.w);
}

// ===================== pipelined MFMA GEMM body (128 x BN, 4 waves) ========
template<int BN>
__device__ __forceinline__ void gemm_body(
    const bf16* __restrict__ A, const bf16* __restrict__ Bt,
    float* __restrict__ Cf,
    int lda, int kbeg, int klen, int ldc, int bx, int by)
{
    constexpr int NFR   = BN / 32;
    constexpr int CALLS = 4 + NFR;
    constexpr int KSRD  = 4 + NFR;
    __shared__ bf16 As[2 * 128 * 64];
    __shared__ bf16 Bs[2 * BN * 64];
    const int tid = threadIdx.x;
    const int wv = tid >> 6, ln = tid & 63;
    const int wr = wv >> 1, wc = wv & 1;
    const size_t m0 = (size_t)by * 128;
    const size_t n0 = (size_t)bx * BN;

    const int lrow = ln >> 3;
    const int lk   = (ln & 7) ^ lrow;

    const bf16* Abase = A  + (m0 + (size_t)wv*32 + lrow) * lda + kbeg + lk*8;
    const bf16* Bbase = Bt + (n0 + (size_t)wv*NFR*8 + lrow) * lda + kbeg + lk*8;
    bf16* AsW = As + wv*2048;
    bf16* BsW = Bs + wv*NFR*512;

    auto stage = [&](int p, int tk) {
        #pragma unroll
        for (int i = 0; i < 4; ++i)
            __builtin_amdgcn_global_load_lds((cg_void*)(Abase + (size_t)i*8*lda + tk),
                                             (lds_void*)(AsW + p*8192 + i*512), 16, 0, 0);
        #pragma unroll
        for (int i = 0; i < NFR; ++i)
            __builtin_amdgcn_global_load_lds((cg_void*)(Bbase + (size_t)i*8*lda + tk),
                                             (lds_void*)(BsW + p*(BN*64) + i*512), 16, 0, 0);
    };

    f32x4 acc[4][NFR] = {};
    const int nt = klen >> 6;

    stage(0, 0);
    stage(1, 64);
    asm volatile("s_waitcnt vmcnt(%0)" :: "n"(CALLS) : "memory");
    __builtin_amdgcn_sched_barrier(0);
    __builtin_amdgcn_s_barrier();

    for (int t = 0; t < nt; ++t) {
        const int p = t & 1;
        const char* Ab = (const char*)As + p * 16384;
        const char* Bb = (const char*)Bs + p * (BN * 128);

        short8 af[4][2], bfr[NFR][2];
        #pragma unroll
        for (int ks = 0; ks < 2; ++ks) {
            const int kbyte = ks*64 + (ln >> 4)*16;
            #pragma unroll
            for (int m = 0; m < 4; ++m) {
                int row = wr*64 + m*16 + (ln & 15);
                af[m][ks] = *(const short8*)(Ab + row*128 + (kbyte ^ ((row & 7) << 4)));
            }
            #pragma unroll
            for (int n = 0; n < NFR; ++n) {
                int row = wc*(BN/2) + n*16 + (ln & 15);
                bfr[n][ks] = *(const short8*)(Bb + row*128 + (kbyte ^ ((row & 7) << 4)));
            }
        }
        asm volatile("s_waitcnt lgkmcnt(%0)" :: "n"(KSRD) : "memory");
        __builtin_amdgcn_sched_barrier(0);
        __builtin_amdgcn_s_setprio(1);
        #pragma unroll
        for (int m = 0; m < 4; ++m)
            #pragma unroll
            for (int n = 0; n < NFR; ++n)
                acc[m][n] = __builtin_amdgcn_mfma_f32_16x16x32_bf16(af[m][0], bfr[n][0], acc[m][n], 0, 0, 0);
        __builtin_amdgcn_s_setprio(0);
        asm volatile("s_waitcnt lgkmcnt(0)" ::: "memory");
        __builtin_amdgcn_sched_barrier(0);
        __builtin_amdgcn_s_barrier();

        const bool more = (t + 2 < nt);
        if (more) stage(p, (t + 2) * 64);
        __builtin_amdgcn_sched_barrier(0);

        __builtin_amdgcn_s_setprio(1);
        #pragma unroll
        for (int m = 0; m < 4; ++m)
            #pragma unroll
            for (int n = 0; n < NFR; ++n)
                acc[m][n] = __builtin_amdgcn_mfma_f32_16x16x32_bf16(af[m][1], bfr[n][1], acc[m][n], 0, 0, 0);
        __builtin_amdgcn_s_setprio(0);

        if (more) { asm volatile("s_waitcnt vmcnt(%0)" :: "n"(CALLS) : "memory"); }
        else      { asm volatile("s_waitcnt vmcnt(0)" ::: "memory"); }
        __builtin_amdgcn_sched_barrier(0);
        __builtin_amdgcn_s_barrier();
    }

    const int cj = ln & 15, rj = ln >> 4;
    #pragma unroll
    for (int m = 0; m < 4; ++m) {
        #pragma unroll
        for (int j = 0; j < 4; ++j) {
            size_t row = m0 + wr*64 + m*16 + rj*4 + j;
            #pragma unroll
            for (int n = 0; n < NFR; ++n) {
                int col = (int)n0 + wc*(BN/2) + n*16 + cj;
                Cf[row * (size_t)ldc + col] = acc[m][n][j];
            }
        }
    }
}

// XCD swizzle: contiguous work chunk per XCD; M-panel (by) is the fast axis.
__device__ __forceinline__ void swz(int& bx, int& by) {
    const int nwg = gridDim.x * gridDim.y;
    int orig = blockIdx.y * gridDim.x + blockIdx.x;
    int wg = (orig & 7) * (nwg >> 3) + (orig >> 3);
    by = wg % gridDim.y;
    bx = wg / gridDim.y;
}

__global__ __launch_bounds__(256) void g_wo(const bf16* __restrict__ A,
                                            const bf16* __restrict__ Bt,
                                            float* __restrict__ C) {
    int bx, by; swz(bx, by);
    gemm_body<64>(A, Bt, C, HID, 0, HID, HID, bx, by);
}

// ===================== fused qkv GEMM + RoPE + layout (R12-proven) =========
__global__ __launch_bounds__(256) void g_qkv_fused(const bf16* __restrict__ A,
                                                   const bf16* __restrict__ Bt,
                                                   const int* __restrict__ pos_ids,
                                                   bf16* __restrict__ Qp,
                                                   bf16* __restrict__ Kp,
                                                   bf16* __restrict__ Vt)
{
    int bx, by; swz(bx, by);
    __shared__ bf16 As[2 * 128 * 64];
    __shared__ bf16 Bs[2 * 64 * 64];
    const int tid = threadIdx.x;
    const int wv = tid >> 6, ln = tid & 63;
    const int wr = wv >> 1, wc = wv & 1;
    const size_t m0 = (size_t)by * 128;
    const size_t n0 = (size_t)bx * 64;

    const int lrow = ln >> 3;
    const int lk   = (ln & 7) ^ lrow;

    const bf16* Abase = A  + (m0 + (size_t)wv*32 + lrow) * HID + lk*8;
    const bf16* Bbase = Bt + (n0 + (size_t)wv*16 + lrow) * HID + lk*8;
    bf16* AsW = As + wv*2048;
    bf16* BsW = Bs + wv*1024;

    auto stage = [&](int p, int tk) {
        #pragma unroll
        for (int i = 0; i < 4; ++i)
            __builtin_amdgcn_global_load_lds((cg_void*)(Abase + (size_t)i*8*HID + tk),
                                             (lds_void*)(AsW + p*8192 + i*512), 16, 0, 0);
        #pragma unroll
        for (int i = 0; i < 2; ++i)
            __builtin_amdgcn_global_load_lds((cg_void*)(Bbase + (size_t)i*8*HID + tk),
                                             (lds_void*)(BsW + p*4096 + i*512), 16, 0, 0);
    };

    f32x4 acc[4][2] = {};
    const int nt = HID >> 6;

    stage(0, 0);
    stage(1, 64);
    asm volatile("s_waitcnt vmcnt(6)" ::: "memory");
    __builtin_amdgcn_sched_barrier(0);
    __builtin_amdgcn_s_barrier();

    for (int t = 0; t < nt; ++t) {
        const int p = t & 1;
        const char* Ab = (const char*)As + p * 16384;
        const char* Bb = (const char*)Bs + p * 8192;

        short8 af[4][2], bfr[2][2];
        #pragma unroll
        for (int ks = 0; ks < 2; ++ks) {
            const int kbyte = ks*64 + (ln >> 4)*16;
            #pragma unroll
            for (int m = 0; m < 4; ++m) {
                int row = wr*64 + m*16 + (ln & 15);
                af[m][ks] = *(const short8*)(Ab + row*128 + (kbyte ^ ((row & 7) << 4)));
            }
            #pragma unroll
            for (int n = 0; n < 2; ++n) {
                int row = wc*16 + n*32 + (ln & 15);
                bfr[n][ks] = *(const short8*)(Bb + row*128 + (kbyte ^ ((row & 7) << 4)));
            }
        }
        asm volatile("s_waitcnt lgkmcnt(6)" ::: "memory");
        __builtin_amdgcn_sched_barrier(0);
        __builtin_amdgcn_s_setprio(1);
        #pragma unroll
        for (int m = 0; m < 4; ++m)
            #pragma unroll
            for (int n = 0; n < 2; ++n)
                acc[m][n] = __builtin_amdgcn_mfma_f32_16x16x32_bf16(af[m][0], bfr[n][0], acc[m][n], 0, 0, 0);
        __builtin_amdgcn_s_setprio(0);
        asm volatile("s_waitcnt lgkmcnt(0)" ::: "memory");
        __builtin_amdgcn_sched_barrier(0);
        __builtin_amdgcn_s_barrier();

        const bool more = (t + 2 < nt);
        if (more) stage(p, (t + 2) * 64);
        __builtin_amdgcn_sched_barrier(0);

        __builtin_amdgcn_s_setprio(1);
        #pragma unroll
        for (int m = 0; m < 4; ++m)
            #pragma unroll
            for (int n = 0; n < 2; ++n)
                acc[m][n] = __builtin_amdgcn_mfma_f32_16x16x32_bf16(af[m][1], bfr[n][1], acc[m][n], 0, 0, 0);
        __builtin_amdgcn_s_setprio(0);

        if (more) { asm volatile("s_waitcnt vmcnt(6)" ::: "memory"); }
        else      { asm volatile("s_waitcnt vmcnt(0)" ::: "memory"); }
        __builtin_amdgcn_sched_barrier(0);
        __builtin_amdgcn_s_barrier();
    }

    const int rj = ln >> 4;
    const int jj = wc*16 + (ln & 15);
    if (bx < 40) {
        const float invf = exp2f(-(float)jj * 0.5916115177913804f);
        bf16* dst = (bx < 32) ? Qp : Kp;
        const int hh = (bx < 32) ? bx : (bx - 32);
        const int nh = (bx < 32) ? 32 : 8;
        #pragma unroll
        for (int m = 0; m < 4; ++m) {
            #pragma unroll
            for (int j = 0; j < 4; ++j) {
                int t = (int)m0 + wr*64 + m*16 + rj*4 + j;
                int s = t & 1023, b = t >> 10;
                float ang = (float)pos_ids[t] * invf;
                float c, sn;
                sincosf(ang, &sn, &c);
                float x1 = acc[m][0][j], x2 = acc[m][1][j];
                size_t base = ((size_t)(b*nh + hh)*1024 + s)*64;
                dst[base + jj]      = __float2bfloat16(x1*c - x2*sn);
                dst[base + jj + 32] = __float2bfloat16(x2*c + x1*sn);
            }
        }
    } else {
        const int hv = bx - 40;
        #pragma unroll
        for (int m = 0; m < 4; ++m) {
            int t0 = (int)m0 + wr*64 + m*16 + rj*4;
            int s0 = t0 & 1023, b = t0 >> 10;
            #pragma unroll
            for (int n = 0; n < 2; ++n) {
                int d = jj + n*32;
                us4 pk;
                #pragma unroll
                for (int j = 0; j < 4; ++j)
                    pk[j] = __bfloat16_as_ushort(__float2bfloat16(acc[m][n][j]));
                *(us4*)(Vt + ((size_t)(b*8 + hv)*64 + d)*1024 + s0) = pk;
            }
        }
    }
}

// ===================== 256x256 2-phase GEMM body (R11/R12-proven) ==========
// EPI: 4 = gateup silu(g)*u -> bf16, 5 = f32 atomicAdd
template<int EPI>
__device__ __forceinline__ void gemm256_body(
    const bf16* __restrict__ A, const bf16* __restrict__ Bt,
    float* __restrict__ Cf, bf16* __restrict__ Cb,
    int lda, int kbeg, int klen, int ldc, int bx, int by)
{
    __shared__ bf16 As[2 * 256 * 64];
    __shared__ bf16 Bs[2 * 256 * 64];
    const int tid = threadIdx.x;
    const int wv = tid >> 6, ln = tid & 63;
    const int wr = wv >> 2, wc = wv & 3;
    const size_t m0 = (size_t)by * 256;
    const size_t n0 = (size_t)bx * 256;

    const int lrow = ln >> 3;
    const int lk   = (ln & 7) ^ lrow;

    const bf16* Abase = A  + (m0 + (size_t)wv*32 + lrow) * lda + kbeg + lk*8;
    const bf16* Bbase = Bt + (n0 + (size_t)wv*32 + lrow) * lda + kbeg + lk*8;
    bf16* AsW = As + wv*2048;
    bf16* BsW = Bs + wv*2048;

    auto stage = [&](int p, int tk) {
        #pragma unroll
        for (int i = 0; i < 4; ++i)
            __builtin_amdgcn_global_load_lds((cg_void*)(Abase + (size_t)i*8*lda + tk),
                                             (lds_void*)(AsW + p*16384 + i*512), 16, 0, 0);
        #pragma unroll
        for (int i = 0; i < 4; ++i)
            __builtin_amdgcn_global_load_lds((cg_void*)(Bbase + (size_t)i*8*lda + tk),
                                             (lds_void*)(BsW + p*16384 + i*512), 16, 0, 0);
    };

    f32x4 acc[8][4] = {};
    const int nt = klen >> 6;

    stage(0, 0);
    stage(1, 64);
    asm volatile("s_waitcnt vmcnt(8)" ::: "memory");
    __builtin_amdgcn_sched_barrier(0);
    __builtin_amdgcn_s_barrier();

    for (int t = 0; t < nt; ++t) {
        const int p = t & 1;
        const char* Ab = (const char*)As + p * 32768;
        const char* Bb = (const char*)Bs + p * 32768;

        short8 af0[8], bf0[4], af1[8], bf1[4];
        {
            const int kbyte = (ln >> 4) * 16;
            #pragma unroll
            for (int m = 0; m < 8; ++m) {
                int row = wr*128 + m*16 + (ln & 15);
                af0[m] = *(const short8*)(Ab + row*128 + (kbyte ^ ((row & 7) << 4)));
            }
            #pragma unroll
            for (int n = 0; n < 4; ++n) {
                int row = wc*64 + n*16 + (ln & 15);
                bf0[n] = *(const short8*)(Bb + row*128 + (kbyte ^ ((row & 7) << 4)));
            }
        }
        {
            const int kbyte = 64 + (ln >> 4) * 16;
            #pragma unroll
            for (int m = 0; m < 8; ++m) {
                int row = wr*128 + m*16 + (ln & 15);
                af1[m] = *(const short8*)(Ab + row*128 + (kbyte ^ ((row & 7) << 4)));
            }
            #pragma unroll
            for (int n = 0; n < 4; ++n) {
                int row = wc*64 + n*16 + (ln & 15);
                bf1[n] = *(const short8*)(Bb + row*128 + (kbyte ^ ((row & 7) << 4)));
            }
        }
        asm volatile("s_waitcnt lgkmcnt(12)" ::: "memory");
        __builtin_amdgcn_sched_barrier(0);
        __builtin_amdgcn_s_setprio(1);
        #pragma unroll
        for (int m = 0; m < 8; ++m)
            #pragma unroll
            for (int n = 0; n < 4; ++n)
                acc[m][n] = __builtin_amdgcn_mfma_f32_16x16x32_bf16(af0[m], bf0[n], acc[m][n], 0, 0, 0);
        __builtin_amdgcn_s_setprio(0);
        asm volatile("s_waitcnt lgkmcnt(0)" ::: "memory");
        __builtin_amdgcn_sched_barrier(0);
        __builtin_amdgcn_s_barrier();

        const bool more = (t + 2 < nt);
        if (more) stage(p, (t + 2) * 64);
        __builtin_amdgcn_sched_barrier(0);

        __builtin_amdgcn_s_setprio(1);
        #pragma unroll
        for (int m = 0; m < 8; ++m)
            #pragma unroll
            for (int n = 0; n < 4; ++n)
                acc[m][n] = __builtin_amdgcn_mfma_f32_16x16x32_bf16(af1[m], bf1[n], acc[m][n], 0, 0, 0);
        __builtin_amdgcn_s_setprio(0);

        if (more) { asm volatile("s_waitcnt vmcnt(8)" ::: "memory"); }
        else      { asm volatile("s_waitcnt vmcnt(0)" ::: "memory"); }
        __builtin_amdgcn_sched_barrier(0);
        __builtin_amdgcn_s_barrier();
    }

    const int cj = ln & 15, rj = ln >> 4;
    if constexpr (EPI == 4) {
        const int slab = (int)(n0 >> 6) + wc;
        #pragma unroll
        for (int m = 0; m < 8; ++m) {
            #pragma unroll
            for (int j = 0; j < 4; ++j) {
                size_t row = m0 + wr*128 + m*16 + rj*4 + j;
                #pragma unroll
                for (int n = 0; n < 2; ++n) {
                    int col = slab*32 + n*16 + cj;
                    float g = acc[m][n][j];
                    float u = acc[m][n+2][j];
                    Cb[row * (size_t)ldc + col] =
                        __float2bfloat16(g / (1.0f + __expf(-g)) * u);
                }
            }
        }
    } else {
        #pragma unroll
        for (int m = 0; m < 8; ++m) {
            #pragma unroll
            for (int j = 0; j < 4; ++j) {
                size_t row = m0 + wr*128 + m*16 + rj*4 + j;
                #pragma unroll
                for (int n = 0; n < 4; ++n) {
                    int col = (int)n0 + wc*64 + n*16 + cj;
                    unsafeAtomicAdd(&Cf[row * (size_t)ldc + col], acc[m][n][j]);
                }
            }
        }
    }
}

__global__ __launch_bounds__(512, 2) void g_gateup(const bf16* __restrict__ A,
                                                   const bf16* __restrict__ Bt,
                                                   bf16* __restrict__ C)
{
    const int nwg = gridDim.x * gridDim.y;
    int orig = blockIdx.y * gridDim.x + blockIdx.x;
    int wg = (orig & 7) * (nwg >> 3) + (orig >> 3);
    const int by = wg % gridDim.y, bx = wg / gridDim.y;
    gemm256_body<4>(A, Bt, nullptr, C, HID, 0, HID, FFN_DIM, bx, by);
}

// down-proj: 256x256 tile, split-K=8 (z), atomicAdd into d_out (holds attn_out)
__global__ __launch_bounds__(512, 2) void g_down(const bf16* __restrict__ A,
                                                 const bf16* __restrict__ Bt,
                                                 float* __restrict__ C)
{
    const int nwg = gridDim.x * gridDim.y;
    int orig = blockIdx.y * gridDim.x + blockIdx.x;
    int wg = (orig & 7) * (nwg >> 3) + (orig >> 3);
    const int by = wg % gridDim.y, bx = wg / gridDim.y;
    gemm256_body<5>(A, Bt, C, nullptr, FFN_DIM, blockIdx.z * 1024, 1024, HID, bx, by);
}

// ===================== MFMA flash attention (bf16, causal, GQA) ============
__global__ __launch_bounds__(256) void attn_mfma(const bf16* __restrict__ Qp,
                                                 const bf16* __restrict__ Kp,
                                                 const bf16* __restrict__ Vt,
                                                 bf16* __restrict__ ctx)
{
    __shared__ bf16 Ks[128 * 64];
    __shared__ bf16 Vs[64 * 128];
    __shared__ bf16 Ps[4 * 32 * 128];
    const int tid = threadIdx.x;
    const int w = tid >> 6, ln = tid & 63;
    const int qt = blockIdx.x, h = blockIdx.y, b = blockIdx.z;
    const int hk = h >> 2;
    const int q0 = qt * 128;

    const bf16* qsec = Qp + ((size_t)(b*32 + h)*1024 + q0 + w*32)*64;
    const bf16* ksec = Kp + ((size_t)(b*8 + hk)*1024)*64;
    const bf16* vsec = Vt + ((size_t)(b*8 + hk))*64*1024;

    short8 qf[2][2];
    #pragma unroll
    for (int f = 0; f < 2; ++f)
        #pragma unroll
        for (int kc = 0; kc < 2; ++kc)
            qf[f][kc] = *(const short8*)(qsec + (size_t)(f*16 + (ln & 15))*64 + kc*32 + (ln >> 4)*8);

    f32x4 acc_o[2][4] = {};
    f32x4 m[2], l[2];
    #pragma unroll
    for (int f = 0; f < 2; ++f)
        #pragma unroll
        for (int j = 0; j < 4; ++j) { m[f][j] = -1e30f; l[f][j] = 0.0f; }

    const int lrow = ln >> 3;
    const int lkk  = (ln & 7) ^ lrow;
    char* PsW = (char*)Ps + w * 8192;

    const int ntiles = qt + 1;
    for (int kt = 0; kt < ntiles; ++kt) {
        const int kv0 = kt * 128;
        {
            const bf16* kbase = ksec + (size_t)(kv0 + w*32 + lrow)*64 + lkk*8;
            bf16* KsW = Ks + w*2048;
            #pragma unroll
            for (int i = 0; i < 4; ++i)
                __builtin_amdgcn_global_load_lds((cg_void*)(kbase + (size_t)i*8*64),
                                                 (lds_void*)(KsW + i*512), 16, 0, 0);
        }
        {
            bf16* VsW = Vs + w*2048;
            #pragma unroll
            for (int i = 0; i < 4; ++i) {
                int d = w*16 + i*4 + (ln >> 4);
                __builtin_amdgcn_global_load_lds(
                    (cg_void*)(vsec + (size_t)d*1024 + kv0 + (((ln & 15) ^ (d & 7))*8)),
                    (lds_void*)(VsW + i*512), 16, 0, 0);
            }
        }
        __syncthreads();

        f32x4 acc_s[2][8] = {};
        #pragma unroll
        for (int c = 0; c < 8; ++c) {
            int kvr = c*16 + (ln & 15);
            const char* krow = (const char*)Ks + kvr*128;
            short8 kf0 = *(const short8*)(krow + (((ln >> 4)*16)      ^ ((kvr & 7) << 4)));
            short8 kf1 = *(const short8*)(krow + ((64 + (ln >> 4)*16) ^ ((kvr & 7) << 4)));
            #pragma unroll
            for (int f = 0; f < 2; ++f) {
                acc_s[f][c] = __builtin_amdgcn_mfma_f32_16x16x32_bf16(qf[f][0], kf0, acc_s[f][c], 0, 0, 0);
                acc_s[f][c] = __builtin_amdgcn_mfma_f32_16x16x32_bf16(qf[f][1], kf1, acc_s[f][c], 0, 0, 0);
            }
        }

        const bool diag = (kt == qt);
        f32x4 vmax[2];
        #pragma unroll
        for (int f = 0; f < 2; ++f)
            #pragma unroll
            for (int j = 0; j < 4; ++j) vmax[f][j] = -1e30f;
        #pragma unroll
        for (int f = 0; f < 2; ++f) {
            #pragma unroll
            for (int c = 0; c < 8; ++c) {
                f32x4 t = acc_s[f][c] * 0.125f;
                if (diag) {
                    int kv = kv0 + c*16 + (ln & 15);
                    int qg = q0 + w*32 + f*16 + (ln >> 4)*4;
                    #pragma unroll
                    for (int j = 0; j < 4; ++j)
                        if (kv > qg + j) t[j] = -1e30f;
                }
                acc_s[f][c] = t;
                #pragma unroll
                for (int j = 0; j < 4; ++j) vmax[f][j] = fmaxf(vmax[f][j], t[j]);
            }
            #pragma unroll
            for (int mk = 1; mk <= 8; mk <<= 1)
                #pragma unroll
                for (int j = 0; j < 4; ++j)
                    vmax[f][j] = fmaxf(vmax[f][j], __shfl_xor(vmax[f][j], mk));
        }

        #pragma unroll
        for (int f = 0; f < 2; ++f) {
            f32x4 r;
            #pragma unroll
            for (int j = 0; j < 4; ++j) {
                float mn = fmaxf(m[f][j], vmax[f][j]);
                r[j] = __expf(m[f][j] - mn);
                m[f][j] = mn;
                l[f][j] *= r[j];
            }
            #pragma unroll
            for (int df = 0; df < 4; ++df)
                #pragma unroll
                for (int j = 0; j < 4; ++j) acc_o[f][df][j] *= r[j];
        }

        f32x4 rs[2] = {};
        #pragma unroll
        for (int f = 0; f < 2; ++f) {
            #pragma unroll
            for (int c = 0; c < 8; ++c) {
                #pragma unroll
                for (int j = 0; j < 4; ++j) {
                    float p = __expf(acc_s[f][c][j] - m[f][j]);
                    rs[f][j] += p;
                    int qloc = f*16 + (ln >> 4)*4 + j;
                    int kvb  = (c*16 + (ln & 15))*2;
                    *(bf16*)(PsW + qloc*256 + (kvb ^ ((qloc & 7) << 4))) = __float2bfloat16(p);
                }
            }
            #pragma unroll
            for (int mk = 1; mk <= 8; mk <<= 1)
                #pragma unroll
                for (int j = 0; j < 4; ++j)
                    rs[f][j] += __shfl_xor(rs[f][j], mk);
            #pragma unroll
            for (int j = 0; j < 4; ++j) l[f][j] += rs[f][j];
        }

        #pragma unroll
        for (int kc = 0; kc < 4; ++kc) {
            short8 pa[2];
            #pragma unroll
            for (int f = 0; f < 2; ++f) {
                int qloc = f*16 + (ln & 15);
                pa[f] = *(const short8*)(PsW + qloc*256 + ((kc*64 + (ln >> 4)*16) ^ ((qloc & 7) << 4)));
            }
            #pragma unroll
            for (int df = 0; df < 4; ++df) {
                int dl = df*16 + (ln & 15);
                short8 vfr = *(const short8*)((const char*)Vs + dl*256 + ((kc*64 + (ln >> 4)*16) ^ ((dl & 7) << 4)));
                #pragma unroll
                for (int f = 0; f < 2; ++f)
                    acc_o[f][df] = __builtin_amdgcn_mfma_f32_16x16x32_bf16(pa[f], vfr, acc_o[f][df], 0, 0, 0);
            }
        }
        __syncthreads();
    }

    #pragma unroll
    for (int f = 0; f < 2; ++f) {
        f32x4 inv;
        #pragma unroll
        for (int j = 0; j < 4; ++j) inv[j] = 1.0f / l[f][j];
        #pragma unroll
        for (int df = 0; df < 4; ++df) {
            #pragma unroll
            for (int j = 0; j < 4; ++j) {
                int q = q0 + w*32 + f*16 + (ln >> 4)*4 + j;
                int d = df*16 + (ln & 15);
                ctx[((size_t)b*1024 + q)*HID + h*64 + d] = __float2bfloat16(acc_o[f][df][j] * inv[j]);
            }
        }
    }
}

// ===================== launch ==============================================
extern "C" void kernel_launch(void* const* d_in, const int* in_sizes, int n_in,
                              void* d_out, int out_size, void* d_ws, size_t ws_size,
                              hipStream_t stream)
{
    const float* hidden = (const float*)d_in[0];
    const float* wq = (const float*)d_in[2];
    const float* wk = (const float*)d_in[3];
    const float* wv = (const float*)d_in[4];
    const float* wo = (const float*)d_in[5];
    const float* n1 = (const float*)d_in[6];
    const float* n2 = (const float*)d_in[7];
    const float* wg = (const float*)d_in[8];
    const float* wu = (const float*)d_in[9];
    const float* wd = (const float*)d_in[10];
    const int*  pos = (const int*)d_in[11];
    float* out = (float*)d_out;
    char* ws = (char*)d_ws;

    // workspace layout (byte offsets)
    bf16* wgu_t  = (bf16*)(ws + 0);           // [16384][2048] interleaved gate/up
    bf16* wd_t   = (bf16*)(ws + 67108864);    // [2048][8192]
    bf16* wqkv_t = (bf16*)(ws + 100663296);   // [3072][2048]
    bf16* wo_t   = (bf16*)(ws + 113246208);   // [2048][2048]
    bf16* normed = (bf16*)(ws + 121634816);   // [2048][2048]
    bf16* Qp     = (bf16*)(ws + 130023424);   // [64][1024][64]
    bf16* ctx    = (bf16*)(ws + 155189248);   // [2048][2048]
    bf16* hb     = (bf16*)(ws + 130023424);   // [2048][8192] aliases Qp+ctx (dead in FFN)
    bf16* Kp     = (bf16*)(ws + 163577856);   // [16][1024][64]
    bf16* Vt     = (bf16*)(ws + 165675008);   // [16][64][1024]

    // weight casts (vectorized 8B writes)
    cast_transpose<<<dim3(32, 32), 256, 0, stream>>>(wq, wqkv_t, 2048, 2048);
    cast_transpose<<<dim3(8, 32),  256, 0, stream>>>(wk, wqkv_t + 4194304, 2048, 512);
    cast_transpose<<<dim3(8, 32),  256, 0, stream>>>(wv, wqkv_t + 5242880, 2048, 512);
    cast_transpose<<<dim3(32, 32), 256, 0, stream>>>(wo, wo_t, 2048, 2048);
    cast_ilv<<<dim3(128, 32), 256, 0, stream>>>(wg, wgu_t, FFN_DIM, 0);
    cast_ilv<<<dim3(128, 32), 256, 0, stream>>>(wu, wgu_t, FFN_DIM, 1);
    cast_transpose<<<dim3(32, 128),256, 0, stream>>>(wd, wd_t, 8192, 2048);

    // 1. normed = rms_norm(hidden)
    rmsnorm_kernel<<<T_TOK, 256, 0, stream>>>(hidden, n1, normed);
    // 2-3. fused qkv GEMM + RoPE + head-major/V-transpose layout
    g_qkv_fused<<<dim3(QKV_N/64, T_TOK/128), 256, 0, stream>>>(
        normed, wqkv_t, pos, Qp, Kp, Vt);
    // 4. MFMA flash attention -> ctx (bf16)
    attn_mfma<<<dim3(8, NHEADS, 2), 256, 0, stream>>>(Qp, Kp, Vt, ctx);
    // 5. attn_out = ctx @ wo -> d_out (f32)
    g_wo<<<dim3(HID/64, T_TOK/128), 256, 0, stream>>>(ctx, wo_t, out);
    // 6. normed2 = rms_norm(attn_out + hidden)
    rmsnorm_add_kernel<<<T_TOK, 256, 0, stream>>>(out, hidden, n2, normed);
    // 7. hb = silu(normed @ wg) * (normed @ wu)  -- 256x256 2-phase GEMM (R12)
    g_gateup<<<dim3(16384/256, T_TOK/256), 512, 0, stream>>>(normed, wgu_t, hb);
    // 8. d_out += hb @ wd  -- 256x256 2-phase, split-K=8, atomic f32 add
    g_down<<<dim3(HID/256, T_TOK/256, 8), 512, 0, stream>>>(hb, wd_t, out);
}

// Round 15
// 477.358 us; speedup vs baseline: 1.1969x; 1.1217x over previous
//
#include <hip/hip_runtime.h>
#include <hip/hip_bf16.h>
#include <cstddef>
#include <cstdint>

#define T_TOK   2048
#define HID     2048
#define NHEADS  32
#define NKV     8
#define HDIM    64
#define FFN_DIM 8192
#define QKV_N   3072

typedef __hip_bfloat16 bf16;
typedef __attribute__((ext_vector_type(8))) short short8;
typedef __attribute__((ext_vector_type(4))) float f32x4;
typedef __attribute__((ext_vector_type(4))) unsigned short us4;

typedef __attribute__((address_space(1))) const void cg_void;
typedef __attribute__((address_space(3))) void lds_void;

// ========== cast + transpose: W[K][N] f32 -> Wt[N][K] bf16 (vectorized) ====
__global__ __launch_bounds__(256) void cast_transpose(const float* __restrict__ in,
                                                      bf16* __restrict__ out,
                                                      int K, int N)
{
    __shared__ bf16 t[64][68];
    const int n0 = blockIdx.x * 64, k0 = blockIdx.y * 64;
    const int g = threadIdx.x & 15, r = threadIdx.x >> 4;
    #pragma unroll
    for (int p = 0; p < 4; ++p) {
        int kr = r + p*16;
        float4 v = *(const float4*)(in + (size_t)(k0 + kr) * N + n0 + g*4);
        t[kr][g*4+0] = __float2bfloat16(v.x);
        t[kr][g*4+1] = __float2bfloat16(v.y);
        t[kr][g*4+2] = __float2bfloat16(v.z);
        t[kr][g*4+3] = __float2bfloat16(v.w);
    }
    __syncthreads();
    #pragma unroll
    for (int p = 0; p < 4; ++p) {
        int nr = r + p*16;
        us4 pk;
        #pragma unroll
        for (int i = 0; i < 4; ++i)
            pk[i] = __bfloat16_as_ushort(t[g*4+i][nr]);
        *(us4*)(out + (size_t)(n0 + nr) * K + k0 + g*4) = pk;
    }
}

// interleaved variant for gate/up fusion: col n -> row (n/32)*64 + is_up*32 + n%32
__global__ __launch_bounds__(256) void cast_ilv(const float* __restrict__ in,
                                                bf16* __restrict__ out,
                                                int N, int is_up)
{
    __shared__ bf16 t[64][68];
    const int n0 = blockIdx.x * 64, k0 = blockIdx.y * 64;
    const int g = threadIdx.x & 15, r = threadIdx.x >> 4;
    #pragma unroll
    for (int p = 0; p < 4; ++p) {
        int kr = r + p*16;
        float4 v = *(const float4*)(in + (size_t)(k0 + kr) * N + n0 + g*4);
        t[kr][g*4+0] = __float2bfloat16(v.x);
        t[kr][g*4+1] = __float2bfloat16(v.y);
        t[kr][g*4+2] = __float2bfloat16(v.z);
        t[kr][g*4+3] = __float2bfloat16(v.w);
    }
    __syncthreads();
    #pragma unroll
    for (int p = 0; p < 4; ++p) {
        int nr = r + p*16;
        int n = n0 + nr;
        int rr = ((n >> 5) << 6) + (is_up << 5) + (n & 31);
        us4 pk;
        #pragma unroll
        for (int i = 0; i < 4; ++i)
            pk[i] = __bfloat16_as_ushort(t[g*4+i][nr]);
        *(us4*)(out + (size_t)rr * HID + k0 + g*4) = pk;
    }
}

// ===================== RMSNorm (f32 in -> bf16 out) ========================
__global__ __launch_bounds__(256) void rmsnorm_kernel(const float* __restrict__ x,
                                                      const float* __restrict__ w,
                                                      bf16* __restrict__ out)
{
    __shared__ float sm[4];
    const int row = blockIdx.x, tid = threadIdx.x;
    const float4* xr = (const float4*)(x + (size_t)row * HID);
    float4 a = xr[tid], b = xr[tid + 256];
    float ss = a.x*a.x + a.y*a.y + a.z*a.z + a.w*a.w
             + b.x*b.x + b.y*b.y + b.z*b.z + b.w*b.w;
    #pragma unroll
    for (int off = 32; off; off >>= 1) ss += __shfl_down(ss, off);
    if ((tid & 63) == 0) sm[tid >> 6] = ss;
    __syncthreads();
    float sc = rsqrtf((sm[0] + sm[1] + sm[2] + sm[3]) * (1.0f / HID) + 1e-5f);
    const float4* wr = (const float4*)w;
    float4 w0 = wr[tid], w1 = wr[tid + 256];
    bf16* o = out + (size_t)row * HID;
    o[tid*4+0] = __float2bfloat16(a.x * sc * w0.x);
    o[tid*4+1] = __float2bfloat16(a.y * sc * w0.y);
    o[tid*4+2] = __float2bfloat16(a.z * sc * w0.z);
    o[tid*4+3] = __float2bfloat16(a.w * sc * w0.w);
    o[1024+tid*4+0] = __float2bfloat16(b.x * sc * w1.x);
    o[1024+tid*4+1] = __float2bfloat16(b.y * sc * w1.y);
    o[1024+tid*4+2] = __float2bfloat16(b.z * sc * w1.z);
    o[1024+tid*4+3] = __float2bfloat16(b.w * sc * w1.w);
}

// rms_norm(a + b) -> bf16
__global__ __launch_bounds__(256) void rmsnorm_add_kernel(const float* __restrict__ xa,
                                                          const float* __restrict__ xb,
                                                          const float* __restrict__ w,
                                                          bf16* __restrict__ out)
{
    __shared__ float sm[4];
    const int row = blockIdx.x, tid = threadIdx.x;
    const float4* ar = (const float4*)(xa + (size_t)row * HID);
    const float4* br = (const float4*)(xb + (size_t)row * HID);
    float4 a0 = ar[tid], a1 = ar[tid + 256];
    float4 b0 = br[tid], b1 = br[tid + 256];
    float4 s0, s1;
    s0.x = a0.x + b0.x; s0.y = a0.y + b0.y; s0.z = a0.z + b0.z; s0.w = a0.w + b0.w;
    s1.x = a1.x + b1.x; s1.y = a1.y + b1.y; s1.z = a1.z + b1.z; s1.w = a1.w + b1.w;
    float ss = s0.x*s0.x + s0.y*s0.y + s0.z*s0.z + s0.w*s0.w
             + s1.x*s1.x + s1.y*s1.y + s1.z*s1.z + s1.w*s1.w;
    #pragma unroll
    for (int off = 32; off; off >>= 1) ss += __shfl_down(ss, off);
    if ((tid & 63) == 0) sm[tid >> 6] = ss;
    __syncthreads();
    float sc = rsqrtf((sm[0] + sm[1] + sm[2] + sm[3]) * (1.0f / HID) + 1e-5f);
    const float4* wr = (const float4*)w;
    float4 w0 = wr[tid], w1 = wr[tid + 256];
    bf16* o = out + (size_t)row * HID;
    o[tid*4+0] = __float2bfloat16(s0.x * sc * w0.x);
    o[tid*4+1] = __float2bfloat16(s0.y * sc * w0.y);
    o[tid*4+2] = __float2bfloat16(s0.z * sc * w0.z);
    o[tid*4+3] = __float2bfloat16(s0.w * sc * w0.w);
    o[1024+tid*4+0] = __float2bfloat16(s1.x * sc * w1.x);
    o[1024+tid*4+1] = __float2bfloat16(s1.y * sc * w1.y);
    o[1024+tid*4+2] = __float2bfloat16(s1.z * sc * w1.z);
    o[1024+tid*4+3] = __float2bfloat16(s1.w * sc * w1.w);
}

// ===================== pipelined MFMA GEMM body (128 x BN, 4 waves) ========
template<int BN>
__device__ __forceinline__ void gemm_body(
    const bf16* __restrict__ A, const bf16* __restrict__ Bt,
    float* __restrict__ Cf,
    int lda, int kbeg, int klen, int ldc, int bx, int by)
{
    constexpr int NFR   = BN / 32;
    constexpr int CALLS = 4 + NFR;
    constexpr int KSRD  = 4 + NFR;
    __shared__ bf16 As[2 * 128 * 64];
    __shared__ bf16 Bs[2 * BN * 64];
    const int tid = threadIdx.x;
    const int wv = tid >> 6, ln = tid & 63;
    const int wr = wv >> 1, wc = wv & 1;
    const size_t m0 = (size_t)by * 128;
    const size_t n0 = (size_t)bx * BN;

    const int lrow = ln >> 3;
    const int lk   = (ln & 7) ^ lrow;

    const bf16* Abase = A  + (m0 + (size_t)wv*32 + lrow) * lda + kbeg + lk*8;
    const bf16* Bbase = Bt + (n0 + (size_t)wv*NFR*8 + lrow) * lda + kbeg + lk*8;
    bf16* AsW = As + wv*2048;
    bf16* BsW = Bs + wv*NFR*512;

    auto stage = [&](int p, int tk) {
        #pragma unroll
        for (int i = 0; i < 4; ++i)
            __builtin_amdgcn_global_load_lds((cg_void*)(Abase + (size_t)i*8*lda + tk),
                                             (lds_void*)(AsW + p*8192 + i*512), 16, 0, 0);
        #pragma unroll
        for (int i = 0; i < NFR; ++i)
            __builtin_amdgcn_global_load_lds((cg_void*)(Bbase + (size_t)i*8*lda + tk),
                                             (lds_void*)(BsW + p*(BN*64) + i*512), 16, 0, 0);
    };

    f32x4 acc[4][NFR] = {};
    const int nt = klen >> 6;

    stage(0, 0);
    stage(1, 64);
    asm volatile("s_waitcnt vmcnt(%0)" :: "n"(CALLS) : "memory");
    __builtin_amdgcn_sched_barrier(0);
    __builtin_amdgcn_s_barrier();

    for (int t = 0; t < nt; ++t) {
        const int p = t & 1;
        const char* Ab = (const char*)As + p * 16384;
        const char* Bb = (const char*)Bs + p * (BN * 128);

        short8 af[4][2], bfr[NFR][2];
        #pragma unroll
        for (int ks = 0; ks < 2; ++ks) {
            const int kbyte = ks*64 + (ln >> 4)*16;
            #pragma unroll
            for (int m = 0; m < 4; ++m) {
                int row = wr*64 + m*16 + (ln & 15);
                af[m][ks] = *(const short8*)(Ab + row*128 + (kbyte ^ ((row & 7) << 4)));
            }
            #pragma unroll
            for (int n = 0; n < NFR; ++n) {
                int row = wc*(BN/2) + n*16 + (ln & 15);
                bfr[n][ks] = *(const short8*)(Bb + row*128 + (kbyte ^ ((row & 7) << 4)));
            }
        }
        asm volatile("s_waitcnt lgkmcnt(%0)" :: "n"(KSRD) : "memory");
        __builtin_amdgcn_sched_barrier(0);
        __builtin_amdgcn_s_setprio(1);
        #pragma unroll
        for (int m = 0; m < 4; ++m)
            #pragma unroll
            for (int n = 0; n < NFR; ++n)
                acc[m][n] = __builtin_amdgcn_mfma_f32_16x16x32_bf16(af[m][0], bfr[n][0], acc[m][n], 0, 0, 0);
        __builtin_amdgcn_s_setprio(0);
        asm volatile("s_waitcnt lgkmcnt(0)" ::: "memory");
        __builtin_amdgcn_sched_barrier(0);
        __builtin_amdgcn_s_barrier();

        const bool more = (t + 2 < nt);
        if (more) stage(p, (t + 2) * 64);
        __builtin_amdgcn_sched_barrier(0);

        __builtin_amdgcn_s_setprio(1);
        #pragma unroll
        for (int m = 0; m < 4; ++m)
            #pragma unroll
            for (int n = 0; n < NFR; ++n)
                acc[m][n] = __builtin_amdgcn_mfma_f32_16x16x32_bf16(af[m][1], bfr[n][1], acc[m][n], 0, 0, 0);
        __builtin_amdgcn_s_setprio(0);

        if (more) { asm volatile("s_waitcnt vmcnt(%0)" :: "n"(CALLS) : "memory"); }
        else      { asm volatile("s_waitcnt vmcnt(0)" ::: "memory"); }
        __builtin_amdgcn_sched_barrier(0);
        __builtin_amdgcn_s_barrier();
    }

    const int cj = ln & 15, rj = ln >> 4;
    #pragma unroll
    for (int m = 0; m < 4; ++m) {
        #pragma unroll
        for (int j = 0; j < 4; ++j) {
            size_t row = m0 + wr*64 + m*16 + rj*4 + j;
            #pragma unroll
            for (int n = 0; n < NFR; ++n) {
                int col = (int)n0 + wc*(BN/2) + n*16 + cj;
                Cf[row * (size_t)ldc + col] = acc[m][n][j];
            }
        }
    }
}

// XCD swizzle: contiguous work chunk per XCD; M-panel (by) is the fast axis.
__device__ __forceinline__ void swz(int& bx, int& by) {
    const int nwg = gridDim.x * gridDim.y;
    int orig = blockIdx.y * gridDim.x + blockIdx.x;
    int wg = (orig & 7) * (nwg >> 3) + (orig >> 3);
    by = wg % gridDim.y;
    bx = wg / gridDim.y;
}

__global__ __launch_bounds__(256) void g_wo(const bf16* __restrict__ A,
                                            const bf16* __restrict__ Bt,
                                            float* __restrict__ C) {
    int bx, by; swz(bx, by);
    gemm_body<64>(A, Bt, C, HID, 0, HID, HID, bx, by);
}

// ===================== fused qkv GEMM + RoPE + layout (R12-proven) =========
__global__ __launch_bounds__(256) void g_qkv_fused(const bf16* __restrict__ A,
                                                   const bf16* __restrict__ Bt,
                                                   const int* __restrict__ pos_ids,
                                                   bf16* __restrict__ Qp,
                                                   bf16* __restrict__ Kp,
                                                   bf16* __restrict__ Vt)
{
    int bx, by; swz(bx, by);
    __shared__ bf16 As[2 * 128 * 64];
    __shared__ bf16 Bs[2 * 64 * 64];
    const int tid = threadIdx.x;
    const int wv = tid >> 6, ln = tid & 63;
    const int wr = wv >> 1, wc = wv & 1;
    const size_t m0 = (size_t)by * 128;
    const size_t n0 = (size_t)bx * 64;

    const int lrow = ln >> 3;
    const int lk   = (ln & 7) ^ lrow;

    const bf16* Abase = A  + (m0 + (size_t)wv*32 + lrow) * HID + lk*8;
    const bf16* Bbase = Bt + (n0 + (size_t)wv*16 + lrow) * HID + lk*8;
    bf16* AsW = As + wv*2048;
    bf16* BsW = Bs + wv*1024;

    auto stage = [&](int p, int tk) {
        #pragma unroll
        for (int i = 0; i < 4; ++i)
            __builtin_amdgcn_global_load_lds((cg_void*)(Abase + (size_t)i*8*HID + tk),
                                             (lds_void*)(AsW + p*8192 + i*512), 16, 0, 0);
        #pragma unroll
        for (int i = 0; i < 2; ++i)
            __builtin_amdgcn_global_load_lds((cg_void*)(Bbase + (size_t)i*8*HID + tk),
                                             (lds_void*)(BsW + p*4096 + i*512), 16, 0, 0);
    };

    f32x4 acc[4][2] = {};
    const int nt = HID >> 6;

    stage(0, 0);
    stage(1, 64);
    asm volatile("s_waitcnt vmcnt(6)" ::: "memory");
    __builtin_amdgcn_sched_barrier(0);
    __builtin_amdgcn_s_barrier();

    for (int t = 0; t < nt; ++t) {
        const int p = t & 1;
        const char* Ab = (const char*)As + p * 16384;
        const char* Bb = (const char*)Bs + p * 8192;

        short8 af[4][2], bfr[2][2];
        #pragma unroll
        for (int ks = 0; ks < 2; ++ks) {
            const int kbyte = ks*64 + (ln >> 4)*16;
            #pragma unroll
            for (int m = 0; m < 4; ++m) {
                int row = wr*64 + m*16 + (ln & 15);
                af[m][ks] = *(const short8*)(Ab + row*128 + (kbyte ^ ((row & 7) << 4)));
            }
            #pragma unroll
            for (int n = 0; n < 2; ++n) {
                int row = wc*16 + n*32 + (ln & 15);
                bfr[n][ks] = *(const short8*)(Bb + row*128 + (kbyte ^ ((row & 7) << 4)));
            }
        }
        asm volatile("s_waitcnt lgkmcnt(6)" ::: "memory");
        __builtin_amdgcn_sched_barrier(0);
        __builtin_amdgcn_s_setprio(1);
        #pragma unroll
        for (int m = 0; m < 4; ++m)
            #pragma unroll
            for (int n = 0; n < 2; ++n)
                acc[m][n] = __builtin_amdgcn_mfma_f32_16x16x32_bf16(af[m][0], bfr[n][0], acc[m][n], 0, 0, 0);
        __builtin_amdgcn_s_setprio(0);
        asm volatile("s_waitcnt lgkmcnt(0)" ::: "memory");
        __builtin_amdgcn_sched_barrier(0);
        __builtin_amdgcn_s_barrier();

        const bool more = (t + 2 < nt);
        if (more) stage(p, (t + 2) * 64);
        __builtin_amdgcn_sched_barrier(0);

        __builtin_amdgcn_s_setprio(1);
        #pragma unroll
        for (int m = 0; m < 4; ++m)
            #pragma unroll
            for (int n = 0; n < 2; ++n)
                acc[m][n] = __builtin_amdgcn_mfma_f32_16x16x32_bf16(af[m][1], bfr[n][1], acc[m][n], 0, 0, 0);
        __builtin_amdgcn_s_setprio(0);

        if (more) { asm volatile("s_waitcnt vmcnt(6)" ::: "memory"); }
        else      { asm volatile("s_waitcnt vmcnt(0)" ::: "memory"); }
        __builtin_amdgcn_sched_barrier(0);
        __builtin_amdgcn_s_barrier();
    }

    const int rj = ln >> 4;
    const int jj = wc*16 + (ln & 15);
    if (bx < 40) {
        const float invf = exp2f(-(float)jj * 0.5916115177913804f);
        bf16* dst = (bx < 32) ? Qp : Kp;
        const int hh = (bx < 32) ? bx : (bx - 32);
        const int nh = (bx < 32) ? 32 : 8;
        #pragma unroll
        for (int m = 0; m < 4; ++m) {
            #pragma unroll
            for (int j = 0; j < 4; ++j) {
                int t = (int)m0 + wr*64 + m*16 + rj*4 + j;
                int s = t & 1023, b = t >> 10;
                float ang = (float)pos_ids[t] * invf;
                float c, sn;
                sincosf(ang, &sn, &c);
                float x1 = acc[m][0][j], x2 = acc[m][1][j];
                size_t base = ((size_t)(b*nh + hh)*1024 + s)*64;
                dst[base + jj]      = __float2bfloat16(x1*c - x2*sn);
                dst[base + jj + 32] = __float2bfloat16(x2*c + x1*sn);
            }
        }
    } else {
        const int hv = bx - 40;
        #pragma unroll
        for (int m = 0; m < 4; ++m) {
            int t0 = (int)m0 + wr*64 + m*16 + rj*4;
            int s0 = t0 & 1023, b = t0 >> 10;
            #pragma unroll
            for (int n = 0; n < 2; ++n) {
                int d = jj + n*32;
                us4 pk;
                #pragma unroll
                for (int j = 0; j < 4; ++j)
                    pk[j] = __bfloat16_as_ushort(__float2bfloat16(acc[m][n][j]));
                *(us4*)(Vt + ((size_t)(b*8 + hv)*64 + d)*1024 + s0) = pk;
            }
        }
    }
}

// ===================== 256x256 2-phase GEMM body (R11/R12-proven) ==========
// EPI: 4 = gateup silu(g)*u -> bf16, 5 = f32 atomicAdd
template<int EPI>
__device__ __forceinline__ void gemm256_body(
    const bf16* __restrict__ A, const bf16* __restrict__ Bt,
    float* __restrict__ Cf, bf16* __restrict__ Cb,
    int lda, int kbeg, int klen, int ldc, int bx, int by)
{
    __shared__ bf16 As[2 * 256 * 64];
    __shared__ bf16 Bs[2 * 256 * 64];
    const int tid = threadIdx.x;
    const int wv = tid >> 6, ln = tid & 63;
    const int wr = wv >> 2, wc = wv & 3;
    const size_t m0 = (size_t)by * 256;
    const size_t n0 = (size_t)bx * 256;

    const int lrow = ln >> 3;
    const int lk   = (ln & 7) ^ lrow;

    const bf16* Abase = A  + (m0 + (size_t)wv*32 + lrow) * lda + kbeg + lk*8;
    const bf16* Bbase = Bt + (n0 + (size_t)wv*32 + lrow) * lda + kbeg + lk*8;
    bf16* AsW = As + wv*2048;
    bf16* BsW = Bs + wv*2048;

    auto stage = [&](int p, int tk) {
        #pragma unroll
        for (int i = 0; i < 4; ++i)
            __builtin_amdgcn_global_load_lds((cg_void*)(Abase + (size_t)i*8*lda + tk),
                                             (lds_void*)(AsW + p*16384 + i*512), 16, 0, 0);
        #pragma unroll
        for (int i = 0; i < 4; ++i)
            __builtin_amdgcn_global_load_lds((cg_void*)(Bbase + (size_t)i*8*lda + tk),
                                             (lds_void*)(BsW + p*16384 + i*512), 16, 0, 0);
    };

    f32x4 acc[8][4] = {};
    const int nt = klen >> 6;

    stage(0, 0);
    stage(1, 64);
    asm volatile("s_waitcnt vmcnt(8)" ::: "memory");
    __builtin_amdgcn_sched_barrier(0);
    __builtin_amdgcn_s_barrier();

    for (int t = 0; t < nt; ++t) {
        const int p = t & 1;
        const char* Ab = (const char*)As + p * 32768;
        const char* Bb = (const char*)Bs + p * 32768;

        short8 af0[8], bf0[4], af1[8], bf1[4];
        {
            const int kbyte = (ln >> 4) * 16;
            #pragma unroll
            for (int m = 0; m < 8; ++m) {
                int row = wr*128 + m*16 + (ln & 15);
                af0[m] = *(const short8*)(Ab + row*128 + (kbyte ^ ((row & 7) << 4)));
            }
            #pragma unroll
            for (int n = 0; n < 4; ++n) {
                int row = wc*64 + n*16 + (ln & 15);
                bf0[n] = *(const short8*)(Bb + row*128 + (kbyte ^ ((row & 7) << 4)));
            }
        }
        {
            const int kbyte = 64 + (ln >> 4) * 16;
            #pragma unroll
            for (int m = 0; m < 8; ++m) {
                int row = wr*128 + m*16 + (ln & 15);
                af1[m] = *(const short8*)(Ab + row*128 + (kbyte ^ ((row & 7) << 4)));
            }
            #pragma unroll
            for (int n = 0; n < 4; ++n) {
                int row = wc*64 + n*16 + (ln & 15);
                bf1[n] = *(const short8*)(Bb + row*128 + (kbyte ^ ((row & 7) << 4)));
            }
        }
        asm volatile("s_waitcnt lgkmcnt(12)" ::: "memory");
        __builtin_amdgcn_sched_barrier(0);
        __builtin_amdgcn_s_setprio(1);
        #pragma unroll
        for (int m = 0; m < 8; ++m)
            #pragma unroll
            for (int n = 0; n < 4; ++n)
                acc[m][n] = __builtin_amdgcn_mfma_f32_16x16x32_bf16(af0[m], bf0[n], acc[m][n], 0, 0, 0);
        __builtin_amdgcn_s_setprio(0);
        asm volatile("s_waitcnt lgkmcnt(0)" ::: "memory");
        __builtin_amdgcn_sched_barrier(0);
        __builtin_amdgcn_s_barrier();

        const bool more = (t + 2 < nt);
        if (more) stage(p, (t + 2) * 64);
        __builtin_amdgcn_sched_barrier(0);

        __builtin_amdgcn_s_setprio(1);
        #pragma unroll
        for (int m = 0; m < 8; ++m)
            #pragma unroll
            for (int n = 0; n < 4; ++n)
                acc[m][n] = __builtin_amdgcn_mfma_f32_16x16x32_bf16(af1[m], bf1[n], acc[m][n], 0, 0, 0);
        __builtin_amdgcn_s_setprio(0);

        if (more) { asm volatile("s_waitcnt vmcnt(8)" ::: "memory"); }
        else      { asm volatile("s_waitcnt vmcnt(0)" ::: "memory"); }
        __builtin_amdgcn_sched_barrier(0);
        __builtin_amdgcn_s_barrier();
    }

    const int cj = ln & 15, rj = ln >> 4;
    if constexpr (EPI == 4) {
        const int slab = (int)(n0 >> 6) + wc;
        #pragma unroll
        for (int m = 0; m < 8; ++m) {
            #pragma unroll
            for (int j = 0; j < 4; ++j) {
                size_t row = m0 + wr*128 + m*16 + rj*4 + j;
                #pragma unroll
                for (int n = 0; n < 2; ++n) {
                    int col = slab*32 + n*16 + cj;
                    float g = acc[m][n][j];
                    float u = acc[m][n+2][j];
                    Cb[row * (size_t)ldc + col] =
                        __float2bfloat16(g / (1.0f + __expf(-g)) * u);
                }
            }
        }
    } else {
        #pragma unroll
        for (int m = 0; m < 8; ++m) {
            #pragma unroll
            for (int j = 0; j < 4; ++j) {
                size_t row = m0 + wr*128 + m*16 + rj*4 + j;
                #pragma unroll
                for (int n = 0; n < 4; ++n) {
                    int col = (int)n0 + wc*64 + n*16 + cj;
                    unsafeAtomicAdd(&Cf[row * (size_t)ldc + col], acc[m][n][j]);
                }
            }
        }
    }
}

__global__ __launch_bounds__(512, 2) void g_gateup(const bf16* __restrict__ A,
                                                   const bf16* __restrict__ Bt,
                                                   bf16* __restrict__ C)
{
    const int nwg = gridDim.x * gridDim.y;
    int orig = blockIdx.y * gridDim.x + blockIdx.x;
    int wg = (orig & 7) * (nwg >> 3) + (orig >> 3);
    const int by = wg % gridDim.y, bx = wg / gridDim.y;
    gemm256_body<4>(A, Bt, nullptr, C, HID, 0, HID, FFN_DIM, bx, by);
}

// down-proj: 256x256 tile, split-K=4 (z), atomicAdd into d_out (holds attn_out)
__global__ __launch_bounds__(512, 2) void g_down(const bf16* __restrict__ A,
                                                 const bf16* __restrict__ Bt,
                                                 float* __restrict__ C)
{
    const int nwg = gridDim.x * gridDim.y;
    int orig = blockIdx.y * gridDim.x + blockIdx.x;
    int wg = (orig & 7) * (nwg >> 3) + (orig >> 3);
    const int by = wg % gridDim.y, bx = wg / gridDim.y;
    gemm256_body<5>(A, Bt, C, nullptr, FFN_DIM, blockIdx.z * 2048, 2048, HID, bx, by);
}

// ===================== MFMA flash attention (bf16, causal, GQA) ============
__global__ __launch_bounds__(256) void attn_mfma(const bf16* __restrict__ Qp,
                                                 const bf16* __restrict__ Kp,
                                                 const bf16* __restrict__ Vt,
                                                 bf16* __restrict__ ctx)
{
    __shared__ bf16 Ks[128 * 64];
    __shared__ bf16 Vs[64 * 128];
    __shared__ bf16 Ps[4 * 32 * 128];
    const int tid = threadIdx.x;
    const int w = tid >> 6, ln = tid & 63;
    const int qt = blockIdx.x, h = blockIdx.y, b = blockIdx.z;
    const int hk = h >> 2;
    const int q0 = qt * 128;

    const bf16* qsec = Qp + ((size_t)(b*32 + h)*1024 + q0 + w*32)*64;
    const bf16* ksec = Kp + ((size_t)(b*8 + hk)*1024)*64;
    const bf16* vsec = Vt + ((size_t)(b*8 + hk))*64*1024;

    short8 qf[2][2];
    #pragma unroll
    for (int f = 0; f < 2; ++f)
        #pragma unroll
        for (int kc = 0; kc < 2; ++kc)
            qf[f][kc] = *(const short8*)(qsec + (size_t)(f*16 + (ln & 15))*64 + kc*32 + (ln >> 4)*8);

    f32x4 acc_o[2][4] = {};
    f32x4 m[2], l[2];
    #pragma unroll
    for (int f = 0; f < 2; ++f)
        #pragma unroll
        for (int j = 0; j < 4; ++j) { m[f][j] = -1e30f; l[f][j] = 0.0f; }

    const int lrow = ln >> 3;
    const int lkk  = (ln & 7) ^ lrow;
    char* PsW = (char*)Ps + w * 8192;

    const int ntiles = qt + 1;
    for (int kt = 0; kt < ntiles; ++kt) {
        const int kv0 = kt * 128;
        {
            const bf16* kbase = ksec + (size_t)(kv0 + w*32 + lrow)*64 + lkk*8;
            bf16* KsW = Ks + w*2048;
            #pragma unroll
            for (int i = 0; i < 4; ++i)
                __builtin_amdgcn_global_load_lds((cg_void*)(kbase + (size_t)i*8*64),
                                                 (lds_void*)(KsW + i*512), 16, 0, 0);
        }
        {
            bf16* VsW = Vs + w*2048;
            #pragma unroll
            for (int i = 0; i < 4; ++i) {
                int d = w*16 + i*4 + (ln >> 4);
                __builtin_amdgcn_global_load_lds(
                    (cg_void*)(vsec + (size_t)d*1024 + kv0 + (((ln & 15) ^ (d & 7))*8)),
                    (lds_void*)(VsW + i*512), 16, 0, 0);
            }
        }
        __syncthreads();

        f32x4 acc_s[2][8] = {};
        #pragma unroll
        for (int c = 0; c < 8; ++c) {
            int kvr = c*16 + (ln & 15);
            const char* krow = (const char*)Ks + kvr*128;
            short8 kf0 = *(const short8*)(krow + (((ln >> 4)*16)      ^ ((kvr & 7) << 4)));
            short8 kf1 = *(const short8*)(krow + ((64 + (ln >> 4)*16) ^ ((kvr & 7) << 4)));
            #pragma unroll
            for (int f = 0; f < 2; ++f) {
                acc_s[f][c] = __builtin_amdgcn_mfma_f32_16x16x32_bf16(qf[f][0], kf0, acc_s[f][c], 0, 0, 0);
                acc_s[f][c] = __builtin_amdgcn_mfma_f32_16x16x32_bf16(qf[f][1], kf1, acc_s[f][c], 0, 0, 0);
            }
        }

        const bool diag = (kt == qt);
        f32x4 vmax[2];
        #pragma unroll
        for (int f = 0; f < 2; ++f)
            #pragma unroll
            for (int j = 0; j < 4; ++j) vmax[f][j] = -1e30f;
        #pragma unroll
        for (int f = 0; f < 2; ++f) {
            #pragma unroll
            for (int c = 0; c < 8; ++c) {
                f32x4 t = acc_s[f][c] * 0.125f;
                if (diag) {
                    int kv = kv0 + c*16 + (ln & 15);
                    int qg = q0 + w*32 + f*16 + (ln >> 4)*4;
                    #pragma unroll
                    for (int j = 0; j < 4; ++j)
                        if (kv > qg + j) t[j] = -1e30f;
                }
                acc_s[f][c] = t;
                #pragma unroll
                for (int j = 0; j < 4; ++j) vmax[f][j] = fmaxf(vmax[f][j], t[j]);
            }
            #pragma unroll
            for (int mk = 1; mk <= 8; mk <<= 1)
                #pragma unroll
                for (int j = 0; j < 4; ++j)
                    vmax[f][j] = fmaxf(vmax[f][j], __shfl_xor(vmax[f][j], mk));
        }

        #pragma unroll
        for (int f = 0; f < 2; ++f) {
            f32x4 r;
            #pragma unroll
            for (int j = 0; j < 4; ++j) {
                float mn = fmaxf(m[f][j], vmax[f][j]);
                r[j] = __expf(m[f][j] - mn);
                m[f][j] = mn;
                l[f][j] *= r[j];
            }
            #pragma unroll
            for (int df = 0; df < 4; ++df)
                #pragma unroll
                for (int j = 0; j < 4; ++j) acc_o[f][df][j] *= r[j];
        }

        f32x4 rs[2] = {};
        #pragma unroll
        for (int f = 0; f < 2; ++f) {
            #pragma unroll
            for (int c = 0; c < 8; ++c) {
                #pragma unroll
                for (int j = 0; j < 4; ++j) {
                    float p = __expf(acc_s[f][c][j] - m[f][j]);
                    rs[f][j] += p;
                    int qloc = f*16 + (ln >> 4)*4 + j;
                    int kvb  = (c*16 + (ln & 15))*2;
                    *(bf16*)(PsW + qloc*256 + (kvb ^ ((qloc & 7) << 4))) = __float2bfloat16(p);
                }
            }
            #pragma unroll
            for (int mk = 1; mk <= 8; mk <<= 1)
                #pragma unroll
                for (int j = 0; j < 4; ++j)
                    rs[f][j] += __shfl_xor(rs[f][j], mk);
            #pragma unroll
            for (int j = 0; j < 4; ++j) l[f][j] += rs[f][j];
        }

        #pragma unroll
        for (int kc = 0; kc < 4; ++kc) {
            short8 pa[2];
            #pragma unroll
            for (int f = 0; f < 2; ++f) {
                int qloc = f*16 + (ln & 15);
                pa[f] = *(const short8*)(PsW + qloc*256 + ((kc*64 + (ln >> 4)*16) ^ ((qloc & 7) << 4)));
            }
            #pragma unroll
            for (int df = 0; df < 4; ++df) {
                int dl = df*16 + (ln & 15);
                short8 vfr = *(const short8*)((const char*)Vs + dl*256 + ((kc*64 + (ln >> 4)*16) ^ ((dl & 7) << 4)));
                #pragma unroll
                for (int f = 0; f < 2; ++f)
                    acc_o[f][df] = __builtin_amdgcn_mfma_f32_16x16x32_bf16(pa[f], vfr, acc_o[f][df], 0, 0, 0);
            }
        }
        __syncthreads();
    }

    #pragma unroll
    for (int f = 0; f < 2; ++f) {
        f32x4 inv;
        #pragma unroll
        for (int j = 0; j < 4; ++j) inv[j] = 1.0f / l[f][j];
        #pragma unroll
        for (int df = 0; df < 4; ++df) {
            #pragma unroll
            for (int j = 0; j < 4; ++j) {
                int q = q0 + w*32 + f*16 + (ln >> 4)*4 + j;
                int d = df*16 + (ln & 15);
                ctx[((size_t)b*1024 + q)*HID + h*64 + d] = __float2bfloat16(acc_o[f][df][j] * inv[j]);
            }
        }
    }
}

// ===================== launch ==============================================
extern "C" void kernel_launch(void* const* d_in, const int* in_sizes, int n_in,
                              void* d_out, int out_size, void* d_ws, size_t ws_size,
                              hipStream_t stream)
{
    const float* hidden = (const float*)d_in[0];
    const float* wq = (const float*)d_in[2];
    const float* wk = (const float*)d_in[3];
    const float* wv = (const float*)d_in[4];
    const float* wo = (const float*)d_in[5];
    const float* n1 = (const float*)d_in[6];
    const float* n2 = (const float*)d_in[7];
    const float* wg = (const float*)d_in[8];
    const float* wu = (const float*)d_in[9];
    const float* wd = (const float*)d_in[10];
    const int*  pos = (const int*)d_in[11];
    float* out = (float*)d_out;
    char* ws = (char*)d_ws;

    // workspace layout (byte offsets)
    bf16* wgu_t  = (bf16*)(ws + 0);           // [16384][2048] interleaved gate/up
    bf16* wd_t   = (bf16*)(ws + 67108864);    // [2048][8192]
    bf16* wqkv_t = (bf16*)(ws + 100663296);   // [3072][2048]
    bf16* wo_t   = (bf16*)(ws + 113246208);   // [2048][2048]
    bf16* normed = (bf16*)(ws + 121634816);   // [2048][2048]
    bf16* Qp     = (bf16*)(ws + 130023424);   // [64][1024][64]
    bf16* ctx    = (bf16*)(ws + 155189248);   // [2048][2048]
    bf16* hb     = (bf16*)(ws + 130023424);   // [2048][8192] aliases Qp+ctx (dead in FFN)
    bf16* Kp     = (bf16*)(ws + 163577856);   // [16][1024][64]
    bf16* Vt     = (bf16*)(ws + 165675008);   // [16][64][1024]

    // weight casts (vectorized 8B writes)
    cast_transpose<<<dim3(32, 32), 256, 0, stream>>>(wq, wqkv_t, 2048, 2048);
    cast_transpose<<<dim3(8, 32),  256, 0, stream>>>(wk, wqkv_t + 4194304, 2048, 512);
    cast_transpose<<<dim3(8, 32),  256, 0, stream>>>(wv, wqkv_t + 5242880, 2048, 512);
    cast_transpose<<<dim3(32, 32), 256, 0, stream>>>(wo, wo_t, 2048, 2048);
    cast_ilv<<<dim3(128, 32), 256, 0, stream>>>(wg, wgu_t, FFN_DIM, 0);
    cast_ilv<<<dim3(128, 32), 256, 0, stream>>>(wu, wgu_t, FFN_DIM, 1);
    cast_transpose<<<dim3(32, 128),256, 0, stream>>>(wd, wd_t, 8192, 2048);

    // 1. normed = rms_norm(hidden)
    rmsnorm_kernel<<<T_TOK, 256, 0, stream>>>(hidden, n1, normed);
    // 2-3. fused qkv GEMM + RoPE + head-major/V-transpose layout
    g_qkv_fused<<<dim3(QKV_N/64, T_TOK/128), 256, 0, stream>>>(
        normed, wqkv_t, pos, Qp, Kp, Vt);
    // 4. MFMA flash attention -> ctx (bf16)
    attn_mfma<<<dim3(8, NHEADS, 2), 256, 0, stream>>>(Qp, Kp, Vt, ctx);
    // 5. attn_out = ctx @ wo -> d_out (f32)
    g_wo<<<dim3(HID/64, T_TOK/128), 256, 0, stream>>>(ctx, wo_t, out);
    // 6. normed2 = rms_norm(attn_out + hidden)
    rmsnorm_add_kernel<<<T_TOK, 256, 0, stream>>>(out, hidden, n2, normed);
    // 7. hb = silu(normed @ wg) * (normed @ wu)  -- 256x256 2-phase GEMM (R12)
    g_gateup<<<dim3(16384/256, T_TOK/256), 512, 0, stream>>>(normed, wgu_t, hb);
    // 8. d_out += hb @ wd  -- 256x256 2-phase, split-K=4, atomic f32 add (R12)
    g_down<<<dim3(HID/256, T_TOK/256, 4), 512, 0, stream>>>(hb, wd_t, out);
}